// Round 12
// baseline (408.010 us; speedup 1.0000x reference)
//
#include <hip/hip_runtime.h>
#include <math.h>

#define B_ 32
#define C_ 256
#define H_ 28
#define W_ 28
#define NPIX 784
#define HK 14
#define NKPIX 196
#define CM 1024
#define EPS_ 1e-5f
#define LN_INVN (1.0f / (C_ * NPIX))

typedef __attribute__((ext_vector_type(8))) short short8;
typedef __attribute__((ext_vector_type(4))) short short4_;
typedef __attribute__((ext_vector_type(4))) float float4_;

// fast GELU: x*sigmoid(x*(2c + 2c*0.044715*x^2)), c=sqrt(2/pi) -- exact
// tanh-GELU identity. |err vs erf-GELU| <= ~1e-3, below bf16 quantization.
__device__ __forceinline__ float gelu_f(float x) {
    float u = x * fmaf(x * x, 0.0713548163f, 1.5957691216f);
    return x / (1.f + __expf(-u));
}
__device__ __forceinline__ short f2bf(float f) {
    union { float f; unsigned u; } x; x.f = f;
    unsigned r = x.u + 0x7FFF + ((x.u >> 16) & 1);
    return (short)(r >> 16);
}
__device__ __forceinline__ float bf2f(short s) {
    union { unsigned u; float f; } x; x.u = ((unsigned)(unsigned short)s) << 16;
    return x.f;
}
// async global->LDS, 16B per lane; LDS dest is wave-uniform base + lane*16
__device__ __forceinline__ void gld16(const short* g, short* l) {
    __builtin_amdgcn_global_load_lds((const __attribute__((address_space(1))) void*)g,
                                     (__attribute__((address_space(3))) void*)l,
                                     16, 0, 0);
}

// ---- convert all 6 weight matrices to bf16 (layout [oc][k], k contiguous) ----
__global__ void wconv_kernel(const float* __restrict__ wq, const float* __restrict__ wk,
                             const float* __restrict__ wv, const float* __restrict__ wo,
                             const float* __restrict__ c1, const float* __restrict__ c2,
                             short* __restrict__ dst) {
    int idx = blockIdx.x * 256 + threadIdx.x;  // total 786432
    const float* src; int off;
    if (idx < 65536)       { src = wq; off = idx; }
    else if (idx < 131072) { src = wk; off = idx - 65536; }
    else if (idx < 196608) { src = wv; off = idx - 131072; }
    else if (idx < 262144) { src = wo; off = idx - 196608; }
    else if (idx < 524288) { src = c1; off = idx - 262144; }
    else                   { src = c2; off = idx - 524288; }
    dst[idx] = f2bf(src[off]);
}

// ---- prep: dwgelu weights/BN2 fold; BN1+c1_b fold (sc1,sh1); BN3+c2_b fold
//      (sc3,sh3); zero the LN2 atomic-stat accumulator ----
__global__ void dwprep_kernel(const float* __restrict__ dww, const float* __restrict__ dwb,
                              const float* __restrict__ g2, const float* __restrict__ b2,
                              const float* __restrict__ m2, const float* __restrict__ v2,
                              const float* __restrict__ c1b, const float* __restrict__ g1,
                              const float* __restrict__ b1, const float* __restrict__ m1,
                              const float* __restrict__ v1,
                              const float* __restrict__ c2b, const float* __restrict__ g3,
                              const float* __restrict__ b3, const float* __restrict__ m3,
                              const float* __restrict__ v3,
                              float* __restrict__ wt, float* __restrict__ sc2,
                              float* __restrict__ sh2, float* __restrict__ sc1,
                              float* __restrict__ sh1, float* __restrict__ sc3,
                              float* __restrict__ sh3, float* __restrict__ st2) {
    int cm = blockIdx.x * 256 + threadIdx.x;  // 1024
    if (blockIdx.x == 0 && threadIdx.x < 64) st2[threadIdx.x] = 0.f;
    float sc = g2[cm] * rsqrtf(v2[cm] + EPS_);
    sc2[cm] = sc;
    sh2[cm] = (dwb[cm] - m2[cm]) * sc + b2[cm];
    float s1 = g1[cm] * rsqrtf(v1[cm] + EPS_);
    sc1[cm] = s1;
    sh1[cm] = (c1b[cm] - m1[cm]) * s1 + b1[cm];
    if (cm < 256) {
        float s3 = g3[cm] * rsqrtf(v3[cm] + EPS_);
        sc3[cm] = s3;
        sh3[cm] = (c2b[cm] - m3[cm]) * s3 + b3[cm];
    }
    #pragma unroll
    for (int tap = 0; tap < 9; ++tap) wt[tap * 1024 + cm] = dww[cm * 9 + tap];
}

// ---- generic LN stats reduce: 32 blocks, each folds cnt (sum,sumsq) pairs ----
__global__ void lnreduce_kernel(const float* __restrict__ part, int cnt,
                                float* __restrict__ out) {
    int b = blockIdx.x;
    const float* p = part + (long)b * cnt * 2;
    float s = 0.f, s2 = 0.f;
    for (int i = threadIdx.x; i < cnt; i += 256) {
        s += p[i * 2];
        s2 += p[i * 2 + 1];
    }
    #pragma unroll
    for (int o = 32; o > 0; o >>= 1) {
        s += __shfl_down(s, o);
        s2 += __shfl_down(s2, o);
    }
    __shared__ float ss[4][2];
    int wv = threadIdx.x >> 6;
    if ((threadIdx.x & 63) == 0) { ss[wv][0] = s; ss[wv][1] = s2; }
    __syncthreads();
    if (threadIdx.x == 0) {
        out[b * 2]     = ss[0][0] + ss[1][0] + ss[2][0] + ss[3][0];
        out[b * 2 + 1] = ss[0][1] + ss[1][1] + ss[2][1] + ss[3][1];
    }
}

// ---- LPU v2: depthwise 3x3 + bias + residual, 4 pixels/thread (float4) ----
__global__ void lpu_kernel(const float* __restrict__ x, const float* __restrict__ w,
                           const float* __restrict__ bias, float* __restrict__ out,
                           float* __restrict__ part) {
    int idx4 = blockIdx.x * 256 + threadIdx.x;   // B*C*196 = 1,605,632 chunks
    int chunk = idx4 % 196;
    int plane = idx4 / 196;                      // b*256 + c
    int c = plane & 255;
    int p0 = chunk * 4;
    int py = p0 / W_, px0 = p0 % W_;             // px0 in {0,4,...,24}
    const float* xp = x + (long)plane * NPIX;
    const float* wc = w + c * 9;
    float4 cc = *(const float4*)(xp + py * W_ + px0);
    float bb = bias[c];
    float acc0 = bb + cc.x, acc1 = bb + cc.y, acc2 = bb + cc.z, acc3 = bb + cc.w;
    #pragma unroll
    for (int dy = -1; dy <= 1; ++dy) {
        int yy = py + dy;
        if (yy < 0 || yy >= H_) continue;
        float4 v = (dy == 0) ? cc : *(const float4*)(xp + yy * W_ + px0);
        float vm1 = (px0 > 0)  ? xp[yy * W_ + px0 - 1] : 0.f;
        float v4  = (px0 < 24) ? xp[yy * W_ + px0 + 4] : 0.f;
        float w0 = wc[(dy + 1) * 3], w1 = wc[(dy + 1) * 3 + 1], w2 = wc[(dy + 1) * 3 + 2];
        acc0 += w0 * vm1 + w1 * v.x + w2 * v.y;
        acc1 += w0 * v.x + w1 * v.y + w2 * v.z;
        acc2 += w0 * v.y + w1 * v.z + w2 * v.w;
        acc3 += w0 * v.z + w1 * v.w + w2 * v4;
    }
    *(float4*)(out + (long)plane * NPIX + p0) = make_float4(acc0, acc1, acc2, acc3);
    float s = acc0 + acc1 + acc2 + acc3;
    float s2 = acc0 * acc0 + acc1 * acc1 + acc2 * acc2 + acc3 * acc3;
    #pragma unroll
    for (int o = 32; o > 0; o >>= 1) {
        s += __shfl_down(s, o);
        s2 += __shfl_down(s2, o);
    }
    __shared__ float ss[4][2];
    int wv = threadIdx.x >> 6;
    if ((threadIdx.x & 63) == 0) { ss[wv][0] = s; ss[wv][1] = s2; }
    __syncthreads();
    if (threadIdx.x == 0) {
        part[blockIdx.x * 2]     = ss[0][0] + ss[1][0] + ss[2][0] + ss[3][0];
        part[blockIdx.x * 2 + 1] = ss[0][1] + ss[1][1] + ss[2][1] + ss[3][1];
    }
}

// ---- transpose + LayerNorm: fp32 [b][256][784] -> bf16 [b][784][256] ----
__global__ void tln_kernel(const float* __restrict__ X, const float* __restrict__ st,
                           short* __restrict__ Y) {
    __shared__ float tile[32][33];
    int p0 = blockIdx.x * 32, c0 = blockIdx.y * 32, b = blockIdx.z;
    int tr = threadIdx.x >> 5, tc = threadIdx.x & 31;
    #pragma unroll
    for (int r = 0; r < 4; ++r) {
        int c = c0 + tr + r * 8, p = p0 + tc;
        tile[tr + r * 8][tc] = (p < NPIX) ? X[((long)b * C_ + c) * NPIX + p] : 0.f;
    }
    float sm = st[b * 2] * LN_INVN;
    float lr = rsqrtf(st[b * 2 + 1] * LN_INVN - sm * sm + EPS_);
    __syncthreads();
    #pragma unroll
    for (int r = 0; r < 4; ++r) {
        int p = p0 + tr + r * 8, c = c0 + tc;
        if (p < NPIX) Y[((long)b * NPIX + p) * C_ + c] = f2bf((tile[tc][tr + r * 8] - sm) * lr);
    }
}

// ---- kv depthwise 2x2 stride-2 (x1 fp32 channel-major -> bf16 pixel-major) ----
__global__ void kvconv_kernel(const float* __restrict__ x1, const float* __restrict__ w,
                              const float* __restrict__ bias, short* __restrict__ out) {
    int idx = blockIdx.x * 256 + threadIdx.x;
    if (idx >= B_ * NKPIX * C_) return;
    int c = idx & 255;
    int rest = idx >> 8;
    int p = rest % NKPIX;
    int b = rest / NKPIX;
    int yo = p / HK, xo = p % HK;
    const float* xb = x1 + ((long)b * C_ + c) * NPIX;
    const float* wc = w + c * 4;
    float a = bias[c]
            + wc[0] * xb[(2 * yo) * W_ + 2 * xo]     + wc[1] * xb[(2 * yo) * W_ + 2 * xo + 1]
            + wc[2] * xb[(2 * yo + 1) * W_ + 2 * xo] + wc[3] * xb[(2 * yo + 1) * W_ + 2 * xo + 1];
    out[idx] = f2bf(a);
}

// ---- MFMA GEMM, batch-merged M, 2-phase double-buffered global_load_lds.
//      SWZ=1: linear grid, XCD-chunked + j-FASTEST decode. ----
template <int EPI, int SWZ>
__global__ __launch_bounds__(256) void mfma_gemm(
    const short* __restrict__ Act, const short* __restrict__ Wb,
    int M, int N, int K,
    const float* __restrict__ bias,
    const float* __restrict__ g, const float* __restrict__ bb,
    const float* __restrict__ res, float* __restrict__ opart,
    short* __restrict__ outh, float* __restrict__ outf) {
    __shared__ short As[2 * 128 * 32];
    __shared__ short Bs[2 * 128 * 32];
    __shared__ float red[16][3];
    const int t = threadIdx.x;
    int ix, jy;
    if (SWZ) {
        const int nwg = gridDim.x;          // multiple of 8
        const int chunk = nwg >> 3;
        const int swz = (blockIdx.x & 7) * chunk + (blockIdx.x >> 3);
        const int ny = N >> 7;              // power of two (2 or 8)
        jy = swz & (ny - 1);
        ix = swz / ny;
    } else {
        ix = blockIdx.x; jy = blockIdx.y;
    }
    const int m0 = ix * 128;
    const int n0 = jy * 128;
    const int w = t >> 6, lane = t & 63;
    const int wm = (w & 1) * 64, wn = (w >> 1) * 64;
    const int col = lane & 15, quad = lane >> 4;

    float4_ acc[4][4];
    #pragma unroll
    for (int i = 0; i < 4; ++i)
        #pragma unroll
        for (int j = 0; j < 4; ++j)
            acc[i][j] = (float4_){0.f, 0.f, 0.f, 0.f};

    const int l4 = lane >> 2;
    const int segsw = (lane & 3) ^ ((l4 ^ (l4 >> 2)) & 3);
    const short* gA = Act + (long)(m0 + w * 16 + l4) * K + segsw * 8;
    const short* gB = Wb  + (long)(n0 + w * 16 + l4) * K + segsw * 8;
    const long rs64 = (long)64 * K;
    const int woff = w * 512;   // w*16 rows * 32 shorts

    const int nk = K >> 5;
    {
        short* dA = As + woff;
        short* dB = Bs + woff;
        gld16(gA, dA);
        gld16(gA + rs64, dA + 2048);
        gld16(gB, dB);
        gld16(gB + rs64, dB + 2048);
    }
    const int slotsw = (quad ^ ((col & 3) ^ ((col >> 2) & 3))) * 8;

    for (int kt = 0; kt < nk; ++kt) {
        __syncthreads();   // buf[kt&1] staged (vmcnt drained); prev reads done
        const int cur = (kt & 1) * 4096;
        if (kt + 1 < nk) {
            const int nxtoff = ((kt + 1) & 1) * 4096 + woff;
            const int k0 = (kt + 1) * 32;
            gld16(gA + k0, As + nxtoff);
            gld16(gA + rs64 + k0, As + nxtoff + 2048);
            gld16(gB + k0, Bs + nxtoff);
            gld16(gB + rs64 + k0, Bs + nxtoff + 2048);
        }
        short8 af[4], bf[4];
        #pragma unroll
        for (int i = 0; i < 4; ++i)
            af[i] = *(const short8*)(As + cur + (wm + i * 16 + col) * 32 + slotsw);
        #pragma unroll
        for (int j = 0; j < 4; ++j)
            bf[j] = *(const short8*)(Bs + cur + (wn + j * 16 + col) * 32 + slotsw);
        #pragma unroll
        for (int i = 0; i < 4; ++i)
            #pragma unroll
            for (int j = 0; j < 4; ++j)
                acc[i][j] = __builtin_amdgcn_mfma_f32_16x16x32_bf16(af[i], bf[j], acc[i][j], 0, 0, 0);
    }

    #pragma unroll
    for (int i = 0; i < 4; ++i) {
        const int pbase = m0 + wm + i * 16 + quad * 4;   // global row (b*784+p)
        float s1 = 0.f, s2s = 0.f;
        int bsmp = 0, psmp = 0;
        if (EPI == 3) { bsmp = pbase / NPIX; psmp = pbase - bsmp * NPIX; }
        #pragma unroll
        for (int j = 0; j < 4; ++j) {
            const int oc = n0 + wn + j * 16 + col;
            if (EPI == 0) {
                float cb = bias[oc];
                #pragma unroll
                for (int r = 0; r < 4; ++r)
                    outh[(long)(pbase + r) * N + oc] = f2bf(acc[i][j][r] + cb);
            } else if (EPI == 1) {
                float sc = g[oc];
                float sh = bb[oc];
                #pragma unroll
                for (int r = 0; r < 4; ++r)
                    outh[(long)(pbase + r) * N + oc] =
                        f2bf(gelu_f(fmaf(acc[i][j][r], sc, sh)));
            } else if (EPI == 2) {
                float cb = bias[oc];
                #pragma unroll
                for (int r = 0; r < 4; ++r) {
                    long jj = (long)(pbase + r) * 256 + oc;
                    float val = acc[i][j][r] + cb + res[jj];
                    outf[jj] = val;
                    s1 += val; s2s += val * val;
                }
            } else {
                float sc = g[oc];
                float sh = bb[oc];
                long basei = ((long)bsmp * 256 + oc) * NPIX + psmp;
                float4 rv = *(const float4*)(res + basei);
                float4 y;
                y.x = fmaf(acc[i][j][0], sc, sh) + rv.x;
                y.y = fmaf(acc[i][j][1], sc, sh) + rv.y;
                y.z = fmaf(acc[i][j][2], sc, sh) + rv.z;
                y.w = fmaf(acc[i][j][3], sc, sh) + rv.w;
                *(float4*)(outf + basei) = y;
            }
        }
        if (EPI == 2) {
            #pragma unroll
            for (int o = 32; o > 0; o >>= 1) {
                s1 += __shfl_down(s1, o);
                s2s += __shfl_down(s2s, o);
            }
            if (lane == 0) {
                red[w * 4 + i][0] = (float)(pbase / NPIX);
                red[w * 4 + i][1] = s1;
                red[w * 4 + i][2] = s2s;
            }
        }
    }
    if (EPI == 2) {
        __syncthreads();
        if (t == 0) {
            int bsA = (int)red[0][0], bsB = -1;
            float a1 = 0.f, a2 = 0.f, b1 = 0.f, b2 = 0.f;
            #pragma unroll
            for (int e = 0; e < 16; ++e) {
                int bs = (int)red[e][0];
                if (bs == bsA) { a1 += red[e][1]; a2 += red[e][2]; }
                else           { bsB = bs; b1 += red[e][1]; b2 += red[e][2]; }
            }
            atomicAdd(&opart[bsA * 2], a1);
            atomicAdd(&opart[bsA * 2 + 1], a2);
            if (bsB >= 0) {
                atomicAdd(&opart[bsB * 2], b1);
                atomicAdd(&opart[bsB * 2 + 1], b2);
            }
        }
    }
}

// ---- MFMA flash attention v4: 8 waves x 16 q-rows (512 threads).
//      Same 128-row tile and per-wave lane math as v3, but each wave's
//      serial chain is HALVED and waves/block DOUBLED (round-11: occupancy
//      16.9% = 1.35 waves/SIMD -> latency exposed). Per-wave state shrinks
//      (1 bq, accO[2], v64[4]) -> lower VGPR -> more co-residency. ----
__global__ __launch_bounds__(512) void attn_kernel(const short* __restrict__ q,
                                                   const short* __restrict__ k,
                                                   const short* __restrict__ v,
                                                   const float* __restrict__ pos_b,
                                                   short* __restrict__ out) {
    __shared__ short Ks[208 * 40];   // [key][d], rows >=196 zero
    __shared__ short Vt[32 * 232];   // [d][key], cols 196..231 zero
    const int qt0 = blockIdx.x * 128;
    const int h = blockIdx.y;
    const int b = blockIdx.z;
    const int t = threadIdx.x;
    const short8 z8 = {0, 0, 0, 0, 0, 0, 0, 0};
    // stage K (208 rows x 4 segs of 16B)
    for (int e = t; e < 832; e += 512) {
        int row = e >> 2, seg = e & 3;
        short8 v8 = (row < NKPIX)
            ? *(const short8*)(k + ((long)(b * NKPIX + row)) * 256 + h * 32 + seg * 8) : z8;
        *(short8*)(Ks + row * 40 + seg * 8) = v8;
    }
    // stage V transposed: vectorized global loads, b16 scatter into LDS
    for (int e = t; e < 784; e += 512) {
        int key = e >> 2, seg = e & 3;
        short8 tv = *(const short8*)(v + ((long)(b * NKPIX + key)) * 256 + h * 32 + seg * 8);
        #pragma unroll
        for (int j = 0; j < 8; ++j) Vt[(seg * 8 + j) * 232 + key] = tv[j];
    }
    // zero Vt pad cols 196..231
    for (int e = t; e < 32 * 36; e += 512) {
        Vt[(e / 36) * 232 + 196 + (e % 36)] = 0;
    }
    __syncthreads();

    const int w = t >> 6, lane = t & 63;   // w in 0..7, 16 q-rows per wave
    const int col = lane & 15, quad = lane >> 4;
    const float scale = 0.17677669529663689f;
    const float4_ z4 = {0.f, 0.f, 0.f, 0.f};

    // Q fragment direct from global (B-operand rows = this wave's 16 queries)
    const int qrow = qt0 + w * 16 + col;
    const bool qvalid = qrow < NPIX;
    const int qe = qvalid ? qrow : 0;
    const short8 bq_ = *(const short8*)(q + ((long)(b * NPIX + qe)) * 256 + h * 32 + quad * 8);
    const float* prow = pos_b + ((long)h * NPIX + qrow) * NKPIX;

    float4_ accO[2] = {z4, z4};
    float lsum = 0.f;

    // redistribution source lanes (fixed per lane)
    const int srcA = col + 32 * (quad & 1);
    const int srcB = srcA + 16;
    const bool hihalf = quad >= 2;

    #pragma unroll
    for (int kc = 0; kc < 4; ++kc) {
        const int base = kc * 64;
        const int ntn = (kc == 3) ? 1 : 4;
        unsigned long long v64[4];
        if (kc == 3) v64[1] = 0ULL;
        // ---- S^T pass: A = K-tile, B = Q-frag; P kept in registers ----
        #pragma unroll
        for (int nt = 0; nt < 4; ++nt) {
            if (nt >= ntn) continue;
            short8 afk = *(const short8*)(Ks + (base + nt * 16 + col) * 40 + quad * 8);
            int keybase = base + nt * 16 + quad * 4;
            bool valid = (keybase < NKPIX) && qvalid;
            float4_ s4 = __builtin_amdgcn_mfma_f32_16x16x32_bf16(afk, bq_, z4, 0, 0, 0);
            float4 pv = make_float4(0.f, 0.f, 0.f, 0.f);
            if (valid)
                pv = *(const float4*)(prow + keybase);
            float p0 = valid ? __expf(s4[0] * scale + pv.x) : 0.f;
            float p1 = valid ? __expf(s4[1] * scale + pv.y) : 0.f;
            float p2 = valid ? __expf(s4[2] * scale + pv.z) : 0.f;
            float p3 = valid ? __expf(s4[3] * scale + pv.w) : 0.f;
            lsum += p0 + p1 + p2 + p3;
            unsigned lo = ((unsigned)(unsigned short)f2bf(p1) << 16) |
                          (unsigned)(unsigned short)f2bf(p0);
            unsigned hi = ((unsigned)(unsigned short)f2bf(p3) << 16) |
                          (unsigned)(unsigned short)f2bf(p2);
            v64[nt] = ((unsigned long long)hi << 32) | lo;
        }
        // ---- PV pass: assemble A-frag via 64-bit shuffles ----
        const int ksn = (kc == 3) ? 1 : 2;
        #pragma unroll
        for (int ks = 0; ks < 2; ++ks) {
            if (ks >= ksn) continue;
            unsigned long long sel = hihalf ? v64[2 * ks + 1] : v64[2 * ks];
            unsigned long long flo = __shfl(sel, srcA, 64);
            unsigned long long fhi = __shfl(sel, srcB, 64);
            union { unsigned long long u; short s[4]; } ul, uh;
            ul.u = flo; uh.u = fhi;
            short8 afp = { ul.s[0], ul.s[1], ul.s[2], ul.s[3],
                           uh.s[0], uh.s[1], uh.s[2], uh.s[3] };
            #pragma unroll
            for (int nt = 0; nt < 2; ++nt) {
                short8 bfv = *(const short8*)(Vt + (nt * 16 + col) * 232 + base + ks * 32 + quad * 8);
                accO[nt] = __builtin_amdgcn_mfma_f32_16x16x32_bf16(afp, bfv, accO[nt], 0, 0, 0);
            }
        }
    }
    // rowsum reduce across quads; broadcast 1/sum back to all quads via shfl
    float s = lsum;
    s += __shfl_xor(s, 16);
    s += __shfl_xor(s, 32);
    // lane holding (col) in quad 0 has the sum; every lane reads lane 'col'
    float rinv_col = 1.f / s;                       // valid on all lanes now
    // epilogue: O in C-layout (m = q = quad*4+r, n = d = nt*16+col);
    // need 1/sum for q-row quad*4+r -> fetch from lane (quad*4+r)
    #pragma unroll
    for (int r = 0; r < 4; ++r) {
        int qq = qt0 + w * 16 + quad * 4 + r;
        if (qq >= NPIX) continue;
        float rinv = __shfl(rinv_col, quad * 4 + r, 64);
        #pragma unroll
        for (int nt = 0; nt < 2; ++nt)
            out[((long)(b * NPIX + qq)) * 256 + h * 32 + nt * 16 + col] =
                f2bf(accO[nt][r] * rinv);
    }
}

// ---- dwconv3x3 + BN2 + GELU v3: 4 vertical pixels x 8 channels per thread ----
__global__ __launch_bounds__(256) void dwgelu_kernel(
    const short* __restrict__ t2, const float* __restrict__ wt,
    const float* __restrict__ sc2, const float* __restrict__ sh2,
    short* __restrict__ t3) {
    const int nchunk = 3136 / 8;   // blocks per XCD chunk
    int bid = blockIdx.x;
    int swz = (bid & 7) * nchunk + (bid >> 3);   // bijective (3136 % 8 == 0)
    int idx = swz * 256 + threadIdx.x;  // B*196*128 = 802,816
    int cm8 = idx & 127;
    int rest = idx >> 7;
    int grp = rest % 196;               // 7 y-groups x 28 columns
    int b = rest / 196;
    int py0 = (grp / 28) * 4;
    int px = grp % 28;
    int cm0 = cm8 * 8;
    const short* tb = t2 + ((long)b * NPIX) * CM + cm0;

    // weights: 9 taps x 8 channels, registers
    float wv[9][8];
    #pragma unroll
    for (int tp = 0; tp < 9; ++tp) {
        float4 a = *(const float4*)(wt + tp * 1024 + cm0);
        float4 bq = *(const float4*)(wt + tp * 1024 + cm0 + 4);
        wv[tp][0] = a.x;  wv[tp][1] = a.y;  wv[tp][2] = a.z;  wv[tp][3] = a.w;
        wv[tp][4] = bq.x; wv[tp][5] = bq.y; wv[tp][6] = bq.z; wv[tp][7] = bq.w;
    }

    float acc[4][8];
    #pragma unroll
    for (int k = 0; k < 4; ++k)
        #pragma unroll
        for (int c = 0; c < 8; ++c) acc[k][c] = 0.f;

    #pragma unroll
    for (int ro = -1; ro <= 4; ++ro) {
        int rr = py0 + ro;
        if (rr < 0 || rr >= H_) continue;
        const short* rowb = tb + (long)(rr * W_ + px) * CM;
        float fm[8], fc[8], fp[8];
        if (px > 0) {
            short8 s = *(const short8*)(rowb - CM);
            #pragma unroll
            for (int c = 0; c < 8; ++c) fm[c] = bf2f(s[c]);
        } else {
            #pragma unroll
            for (int c = 0; c < 8; ++c) fm[c] = 0.f;
        }
        {
            short8 s = *(const short8*)(rowb);
            #pragma unroll
            for (int c = 0; c < 8; ++c) fc[c] = bf2f(s[c]);
        }
        if (px < 27) {
            short8 s = *(const short8*)(rowb + CM);
            #pragma unroll
            for (int c = 0; c < 8; ++c) fp[c] = bf2f(s[c]);
        } else {
            #pragma unroll
            for (int c = 0; c < 8; ++c) fp[c] = 0.f;
        }
        #pragma unroll
        for (int k = 0; k < 4; ++k) {
            const int tr = ro - k + 1;     // tap row for output k (compile-time)
            if (tr < 0 || tr > 2) continue;
            #pragma unroll
            for (int c = 0; c < 8; ++c)
                acc[k][c] = fmaf(wv[tr * 3][c], fm[c],
                            fmaf(wv[tr * 3 + 1][c], fc[c],
                            fmaf(wv[tr * 3 + 2][c], fp[c], acc[k][c])));
        }
    }

    float4 sa = *(const float4*)(sc2 + cm0);
    float4 sb = *(const float4*)(sc2 + cm0 + 4);
    float4 ha = *(const float4*)(sh2 + cm0);
    float4 hb = *(const float4*)(sh2 + cm0 + 4);
    float scl[8] = {sa.x, sa.y, sa.z, sa.w, sb.x, sb.y, sb.z, sb.w};
    float shf[8] = {ha.x, ha.y, ha.z, ha.w, hb.x, hb.y, hb.z, hb.w};
    #pragma unroll
    for (int k = 0; k < 4; ++k) {
        short8 ov;
        #pragma unroll
        for (int c = 0; c < 8; ++c)
            ov[c] = f2bf(gelu_f(fmaf(acc[k][c], scl[c], shf[c])));
        *(short8*)(t3 + ((long)b * NPIX + (py0 + k) * W_ + px) * CM + cm0) = ov;
    }
}

extern "C" void kernel_launch(void* const* d_in, const int* in_sizes, int n_in,
                              void* d_out, int out_size, void* d_ws, size_t ws_size,
                              hipStream_t stream) {
    const float* x     = (const float*)d_in[0];
    const float* lpu_w = (const float*)d_in[1];
    const float* lpu_b = (const float*)d_in[2];
    const float* dw_w  = (const float*)d_in[3];
    const float* dw_b  = (const float*)d_in[4];
    const float* wq    = (const float*)d_in[5];
    const float* bq    = (const float*)d_in[6];
    const float* wk    = (const float*)d_in[7];
    const float* bk    = (const float*)d_in[8];
    const float* wv    = (const float*)d_in[9];
    const float* bv    = (const float*)d_in[10];
    const float* wo    = (const float*)d_in[11];
    const float* bo    = (const float*)d_in[12];
    const float* posb  = (const float*)d_in[13];
    const float* c1_w  = (const float*)d_in[14];
    const float* c1_b  = (const float*)d_in[15];
    const float* bn1_g = (const float*)d_in[16];
    const float* bn1_b = (const float*)d_in[17];
    const float* bn1_m = (const float*)d_in[18];
    const float* bn1_v = (const float*)d_in[19];
    const float* dw2_w = (const float*)d_in[20];
    const float* dw2_b = (const float*)d_in[21];
    const float* bn2_g = (const float*)d_in[22];
    const float* bn2_b = (const float*)d_in[23];
    const float* bn2_m = (const float*)d_in[24];
    const float* bn2_v = (const float*)d_in[25];
    const float* c2_w  = (const float*)d_in[26];
    const float* c2_b  = (const float*)d_in[27];
    const float* bn3_g = (const float*)d_in[28];
    const float* bn3_b = (const float*)d_in[29];
    const float* bn3_m = (const float*)d_in[30];
    const float* bn3_v = (const float*)d_in[31];

    const long n1  = (long)B_ * C_ * NPIX;    // 6,422,528
    const long nkv = (long)B_ * C_ * NKPIX;   // 1,605,632
    const long nm  = (long)B_ * CM * NPIX;    // 25,690,112
    const int  nblk1 = (int)(n1 / 1024);      // 6272 lpu blocks (196 per sample)
    const int  MQ = B_ * NPIX;                // 25088 = 196*128 (exact)
    const int  MKV = B_ * NKPIX;              // 6272  = 49*128  (exact)

    char* base = (char*)d_ws;
    float* x1   = (float*)base; base += n1 * 4;
    float* x2c  = (float*)base; base += n1 * 4;
    short* x1n  = (short*)base; base += n1 * 2;
    short* qb   = (short*)base; base += n1 * 2;
    short* tmpb = (short*)base; base += n1 * 2;
    short* t1n  = (short*)base; base += n1 * 2;
    short* kvb  = (short*)base; base += nkv * 2;
    short* kb   = (short*)base; base += nkv * 2;
    short* vb   = (short*)base; base += nkv * 2;
    short* t2   = (short*)base; base += nm * 2;
    short* t3   = (short*)base; base += nm * 2;
    short* wbf  = (short*)base; base += 786432L * 2;
    float* stats = (float*)base; base += 128 * 4;
    float* dwt   = (float*)base; base += 9216 * 4;   // [9][1024]
    float* dsc   = (float*)base; base += 1024 * 4;
    float* dsh   = (float*)base; base += 1024 * 4;
    float* dsc1  = (float*)base; base += 1024 * 4;
    float* dsh1  = (float*)base; base += 1024 * 4;
    float* dsc3  = (float*)base; base += 256 * 4;
    float* dsh3  = (float*)base; base += 256 * 4;
    float* part1 = (float*)base; base += (long)nblk1 * 2 * 4;
    float* outp = (float*)d_out;

    wconv_kernel<<<3072, 256, 0, stream>>>(wq, wk, wv, wo, c1_w, c2_w, wbf);
    dwprep_kernel<<<4, 256, 0, stream>>>(dw2_w, dw2_b, bn2_g, bn2_b, bn2_m, bn2_v,
                                         c1_b, bn1_g, bn1_b, bn1_m, bn1_v,
                                         c2_b, bn3_g, bn3_b, bn3_m, bn3_v,
                                         dwt, dsc, dsh, dsc1, dsh1, dsc3, dsh3,
                                         stats + 64);
    lpu_kernel<<<nblk1, 256, 0, stream>>>(x, lpu_w, lpu_b, x1, part1);
    lnreduce_kernel<<<B_, 256, 0, stream>>>(part1, nblk1 / B_, stats);
    kvconv_kernel<<<(int)((nkv + 255) / 256), 256, 0, stream>>>(x1, dw_w, dw_b, kvb);
    tln_kernel<<<dim3(25, 8, B_), 256, 0, stream>>>(x1, stats, x1n);
    // q projection: swizzled linear grid 392 = (196 i) x (2 j), j-fastest
    mfma_gemm<0, 1><<<392, 256, 0, stream>>>(
        x1n, wbf, MQ, 256, 256, bq, nullptr, nullptr,
        nullptr, nullptr, qb, nullptr);
    // k/v projections: 98 blocks (not %8) -> plain 2D grid
    mfma_gemm<0, 0><<<dim3(MKV / 128, 2), 256, 0, stream>>>(
        kvb, wbf + 65536, MKV, 256, 256, bk, nullptr, nullptr,
        nullptr, nullptr, kb, nullptr);
    mfma_gemm<0, 0><<<dim3(MKV / 128, 2), 256, 0, stream>>>(
        kvb, wbf + 131072, MKV, 256, 256, bv, nullptr, nullptr,
        nullptr, nullptr, vb, nullptr);
    attn_kernel<<<dim3(7, 8, B_), 512, 0, stream>>>(qb, kb, vb, posb, tmpb);
    // wo + flat residual + LN2 stats (swizzled 392)
    mfma_gemm<2, 1><<<392, 256, 0, stream>>>(
        tmpb, wbf + 196608, MQ, 256, 256, bo, nullptr, nullptr,
        x1, stats + 64, nullptr, x2c);
    tln_kernel<<<dim3(25, 8, B_), 256, 0, stream>>>(x2c, stats + 64, t1n);
    // conv1 1x1 + folded BN1 + fast GELU (swizzled 1568 = 196 x 8, j-fastest)
    mfma_gemm<1, 1><<<1568, 256, 0, stream>>>(
        t1n, wbf + 262144, MQ, CM, 256, nullptr, dsc1, dsh1,
        nullptr, nullptr, t2, nullptr);
    dwgelu_kernel<<<3136, 256, 0, stream>>>(t2, dwt, dsc, dsh, t3);
    // conv2 1x1 + folded BN3 + residual -> d_out (swizzled 392)
    mfma_gemm<3, 1><<<392, 256, 0, stream>>>(
        t3, wbf + 524288, MQ, 256, 1024, nullptr, dsc3, dsh3,
        x2c, nullptr, nullptr, outp);
}

// Round 13
// 404.963 us; speedup vs baseline: 1.0075x; 1.0075x over previous
//
#include <hip/hip_runtime.h>
#include <math.h>

#define B_ 32
#define C_ 256
#define H_ 28
#define W_ 28
#define NPIX 784
#define HK 14
#define NKPIX 196
#define CM 1024
#define EPS_ 1e-5f
#define LN_INVN (1.0f / (C_ * NPIX))

typedef __attribute__((ext_vector_type(8))) short short8;
typedef __attribute__((ext_vector_type(4))) short short4_;
typedef __attribute__((ext_vector_type(4))) float float4_;

// fast GELU: x*sigmoid(x*(2c + 2c*0.044715*x^2)), c=sqrt(2/pi) -- exact
// tanh-GELU identity. |err vs erf-GELU| <= ~1e-3, below bf16 quantization.
__device__ __forceinline__ float gelu_f(float x) {
    float u = x * fmaf(x * x, 0.0713548163f, 1.5957691216f);
    return x / (1.f + __expf(-u));
}
__device__ __forceinline__ short f2bf(float f) {
    union { float f; unsigned u; } x; x.f = f;
    unsigned r = x.u + 0x7FFF + ((x.u >> 16) & 1);
    return (short)(r >> 16);
}
__device__ __forceinline__ float bf2f(short s) {
    union { unsigned u; float f; } x; x.u = ((unsigned)(unsigned short)s) << 16;
    return x.f;
}
// async global->LDS, 16B per lane; LDS dest is wave-uniform base + lane*16
__device__ __forceinline__ void gld16(const short* g, short* l) {
    __builtin_amdgcn_global_load_lds((const __attribute__((address_space(1))) void*)g,
                                     (__attribute__((address_space(3))) void*)l,
                                     16, 0, 0);
}

// ---- convert all 6 weight matrices to bf16 (layout [oc][k], k contiguous) ----
__global__ void wconv_kernel(const float* __restrict__ wq, const float* __restrict__ wk,
                             const float* __restrict__ wv, const float* __restrict__ wo,
                             const float* __restrict__ c1, const float* __restrict__ c2,
                             short* __restrict__ dst) {
    int idx = blockIdx.x * 256 + threadIdx.x;  // total 786432
    const float* src; int off;
    if (idx < 65536)       { src = wq; off = idx; }
    else if (idx < 131072) { src = wk; off = idx - 65536; }
    else if (idx < 196608) { src = wv; off = idx - 131072; }
    else if (idx < 262144) { src = wo; off = idx - 196608; }
    else if (idx < 524288) { src = c1; off = idx - 262144; }
    else                   { src = c2; off = idx - 524288; }
    dst[idx] = f2bf(src[off]);
}

// ---- prep: dwgelu weights/BN2 fold; BN1+c1_b fold (sc1,sh1); BN3+c2_b fold
//      (sc3,sh3); zero the LN2 atomic-stat accumulator ----
__global__ void dwprep_kernel(const float* __restrict__ dww, const float* __restrict__ dwb,
                              const float* __restrict__ g2, const float* __restrict__ b2,
                              const float* __restrict__ m2, const float* __restrict__ v2,
                              const float* __restrict__ c1b, const float* __restrict__ g1,
                              const float* __restrict__ b1, const float* __restrict__ m1,
                              const float* __restrict__ v1,
                              const float* __restrict__ c2b, const float* __restrict__ g3,
                              const float* __restrict__ b3, const float* __restrict__ m3,
                              const float* __restrict__ v3,
                              float* __restrict__ wt, float* __restrict__ sc2,
                              float* __restrict__ sh2, float* __restrict__ sc1,
                              float* __restrict__ sh1, float* __restrict__ sc3,
                              float* __restrict__ sh3, float* __restrict__ st2) {
    int cm = blockIdx.x * 256 + threadIdx.x;  // 1024
    if (blockIdx.x == 0 && threadIdx.x < 64) st2[threadIdx.x] = 0.f;
    float sc = g2[cm] * rsqrtf(v2[cm] + EPS_);
    sc2[cm] = sc;
    sh2[cm] = (dwb[cm] - m2[cm]) * sc + b2[cm];
    float s1 = g1[cm] * rsqrtf(v1[cm] + EPS_);
    sc1[cm] = s1;
    sh1[cm] = (c1b[cm] - m1[cm]) * s1 + b1[cm];
    if (cm < 256) {
        float s3 = g3[cm] * rsqrtf(v3[cm] + EPS_);
        sc3[cm] = s3;
        sh3[cm] = (c2b[cm] - m3[cm]) * s3 + b3[cm];
    }
    #pragma unroll
    for (int tap = 0; tap < 9; ++tap) wt[tap * 1024 + cm] = dww[cm * 9 + tap];
}

// ---- generic LN stats reduce: 32 blocks, each folds cnt (sum,sumsq) pairs ----
__global__ void lnreduce_kernel(const float* __restrict__ part, int cnt,
                                float* __restrict__ out) {
    int b = blockIdx.x;
    const float* p = part + (long)b * cnt * 2;
    float s = 0.f, s2 = 0.f;
    for (int i = threadIdx.x; i < cnt; i += 256) {
        s += p[i * 2];
        s2 += p[i * 2 + 1];
    }
    #pragma unroll
    for (int o = 32; o > 0; o >>= 1) {
        s += __shfl_down(s, o);
        s2 += __shfl_down(s2, o);
    }
    __shared__ float ss[4][2];
    int wv = threadIdx.x >> 6;
    if ((threadIdx.x & 63) == 0) { ss[wv][0] = s; ss[wv][1] = s2; }
    __syncthreads();
    if (threadIdx.x == 0) {
        out[b * 2]     = ss[0][0] + ss[1][0] + ss[2][0] + ss[3][0];
        out[b * 2 + 1] = ss[0][1] + ss[1][1] + ss[2][1] + ss[3][1];
    }
}

// ---- LPU v2: depthwise 3x3 + bias + residual, 4 pixels/thread (float4) ----
__global__ void lpu_kernel(const float* __restrict__ x, const float* __restrict__ w,
                           const float* __restrict__ bias, float* __restrict__ out,
                           float* __restrict__ part) {
    int idx4 = blockIdx.x * 256 + threadIdx.x;   // B*C*196 = 1,605,632 chunks
    int chunk = idx4 % 196;
    int plane = idx4 / 196;                      // b*256 + c
    int c = plane & 255;
    int p0 = chunk * 4;
    int py = p0 / W_, px0 = p0 % W_;             // px0 in {0,4,...,24}
    const float* xp = x + (long)plane * NPIX;
    const float* wc = w + c * 9;
    float4 cc = *(const float4*)(xp + py * W_ + px0);
    float bb = bias[c];
    float acc0 = bb + cc.x, acc1 = bb + cc.y, acc2 = bb + cc.z, acc3 = bb + cc.w;
    #pragma unroll
    for (int dy = -1; dy <= 1; ++dy) {
        int yy = py + dy;
        if (yy < 0 || yy >= H_) continue;
        float4 v = (dy == 0) ? cc : *(const float4*)(xp + yy * W_ + px0);
        float vm1 = (px0 > 0)  ? xp[yy * W_ + px0 - 1] : 0.f;
        float v4  = (px0 < 24) ? xp[yy * W_ + px0 + 4] : 0.f;
        float w0 = wc[(dy + 1) * 3], w1 = wc[(dy + 1) * 3 + 1], w2 = wc[(dy + 1) * 3 + 2];
        acc0 += w0 * vm1 + w1 * v.x + w2 * v.y;
        acc1 += w0 * v.x + w1 * v.y + w2 * v.z;
        acc2 += w0 * v.y + w1 * v.z + w2 * v.w;
        acc3 += w0 * v.z + w1 * v.w + w2 * v4;
    }
    *(float4*)(out + (long)plane * NPIX + p0) = make_float4(acc0, acc1, acc2, acc3);
    float s = acc0 + acc1 + acc2 + acc3;
    float s2 = acc0 * acc0 + acc1 * acc1 + acc2 * acc2 + acc3 * acc3;
    #pragma unroll
    for (int o = 32; o > 0; o >>= 1) {
        s += __shfl_down(s, o);
        s2 += __shfl_down(s2, o);
    }
    __shared__ float ss[4][2];
    int wv = threadIdx.x >> 6;
    if ((threadIdx.x & 63) == 0) { ss[wv][0] = s; ss[wv][1] = s2; }
    __syncthreads();
    if (threadIdx.x == 0) {
        part[blockIdx.x * 2]     = ss[0][0] + ss[1][0] + ss[2][0] + ss[3][0];
        part[blockIdx.x * 2 + 1] = ss[0][1] + ss[1][1] + ss[2][1] + ss[3][1];
    }
}

// ---- transpose + LayerNorm: fp32 [b][256][784] -> bf16 [b][784][256] ----
__global__ void tln_kernel(const float* __restrict__ X, const float* __restrict__ st,
                           short* __restrict__ Y) {
    __shared__ float tile[32][33];
    int p0 = blockIdx.x * 32, c0 = blockIdx.y * 32, b = blockIdx.z;
    int tr = threadIdx.x >> 5, tc = threadIdx.x & 31;
    #pragma unroll
    for (int r = 0; r < 4; ++r) {
        int c = c0 + tr + r * 8, p = p0 + tc;
        tile[tr + r * 8][tc] = (p < NPIX) ? X[((long)b * C_ + c) * NPIX + p] : 0.f;
    }
    float sm = st[b * 2] * LN_INVN;
    float lr = rsqrtf(st[b * 2 + 1] * LN_INVN - sm * sm + EPS_);
    __syncthreads();
    #pragma unroll
    for (int r = 0; r < 4; ++r) {
        int p = p0 + tr + r * 8, c = c0 + tc;
        if (p < NPIX) Y[((long)b * NPIX + p) * C_ + c] = f2bf((tile[tc][tr + r * 8] - sm) * lr);
    }
}

// ---- kv depthwise 2x2 stride-2 (x1 fp32 channel-major -> bf16 pixel-major) ----
__global__ void kvconv_kernel(const float* __restrict__ x1, const float* __restrict__ w,
                              const float* __restrict__ bias, short* __restrict__ out) {
    int idx = blockIdx.x * 256 + threadIdx.x;
    if (idx >= B_ * NKPIX * C_) return;
    int c = idx & 255;
    int rest = idx >> 8;
    int p = rest % NKPIX;
    int b = rest / NKPIX;
    int yo = p / HK, xo = p % HK;
    const float* xb = x1 + ((long)b * C_ + c) * NPIX;
    const float* wc = w + c * 4;
    float a = bias[c]
            + wc[0] * xb[(2 * yo) * W_ + 2 * xo]     + wc[1] * xb[(2 * yo) * W_ + 2 * xo + 1]
            + wc[2] * xb[(2 * yo + 1) * W_ + 2 * xo] + wc[3] * xb[(2 * yo + 1) * W_ + 2 * xo + 1];
    out[idx] = f2bf(a);
}

// ---- MFMA GEMM, batch-merged M, 2-phase double-buffered global_load_lds.
//      SWZ=1: linear grid, XCD-chunked + j-FASTEST decode. ----
template <int EPI, int SWZ>
__global__ __launch_bounds__(256) void mfma_gemm(
    const short* __restrict__ Act, const short* __restrict__ Wb,
    int M, int N, int K,
    const float* __restrict__ bias,
    const float* __restrict__ g, const float* __restrict__ bb,
    const float* __restrict__ res, float* __restrict__ opart,
    short* __restrict__ outh, float* __restrict__ outf) {
    __shared__ short As[2 * 128 * 32];
    __shared__ short Bs[2 * 128 * 32];
    __shared__ float red[16][3];
    const int t = threadIdx.x;
    int ix, jy;
    if (SWZ) {
        const int nwg = gridDim.x;          // multiple of 8
        const int chunk = nwg >> 3;
        const int swz = (blockIdx.x & 7) * chunk + (blockIdx.x >> 3);
        const int ny = N >> 7;              // power of two (2 or 8)
        jy = swz & (ny - 1);
        ix = swz / ny;
    } else {
        ix = blockIdx.x; jy = blockIdx.y;
    }
    const int m0 = ix * 128;
    const int n0 = jy * 128;
    const int w = t >> 6, lane = t & 63;
    const int wm = (w & 1) * 64, wn = (w >> 1) * 64;
    const int col = lane & 15, quad = lane >> 4;

    float4_ acc[4][4];
    #pragma unroll
    for (int i = 0; i < 4; ++i)
        #pragma unroll
        for (int j = 0; j < 4; ++j)
            acc[i][j] = (float4_){0.f, 0.f, 0.f, 0.f};

    const int l4 = lane >> 2;
    const int segsw = (lane & 3) ^ ((l4 ^ (l4 >> 2)) & 3);
    const short* gA = Act + (long)(m0 + w * 16 + l4) * K + segsw * 8;
    const short* gB = Wb  + (long)(n0 + w * 16 + l4) * K + segsw * 8;
    const long rs64 = (long)64 * K;
    const int woff = w * 512;   // w*16 rows * 32 shorts

    const int nk = K >> 5;
    {
        short* dA = As + woff;
        short* dB = Bs + woff;
        gld16(gA, dA);
        gld16(gA + rs64, dA + 2048);
        gld16(gB, dB);
        gld16(gB + rs64, dB + 2048);
    }
    const int slotsw = (quad ^ ((col & 3) ^ ((col >> 2) & 3))) * 8;

    for (int kt = 0; kt < nk; ++kt) {
        __syncthreads();   // buf[kt&1] staged (vmcnt drained); prev reads done
        const int cur = (kt & 1) * 4096;
        if (kt + 1 < nk) {
            const int nxtoff = ((kt + 1) & 1) * 4096 + woff;
            const int k0 = (kt + 1) * 32;
            gld16(gA + k0, As + nxtoff);
            gld16(gA + rs64 + k0, As + nxtoff + 2048);
            gld16(gB + k0, Bs + nxtoff);
            gld16(gB + rs64 + k0, Bs + nxtoff + 2048);
        }
        short8 af[4], bf[4];
        #pragma unroll
        for (int i = 0; i < 4; ++i)
            af[i] = *(const short8*)(As + cur + (wm + i * 16 + col) * 32 + slotsw);
        #pragma unroll
        for (int j = 0; j < 4; ++j)
            bf[j] = *(const short8*)(Bs + cur + (wn + j * 16 + col) * 32 + slotsw);
        #pragma unroll
        for (int i = 0; i < 4; ++i)
            #pragma unroll
            for (int j = 0; j < 4; ++j)
                acc[i][j] = __builtin_amdgcn_mfma_f32_16x16x32_bf16(af[i], bf[j], acc[i][j], 0, 0, 0);
    }

    #pragma unroll
    for (int i = 0; i < 4; ++i) {
        const int pbase = m0 + wm + i * 16 + quad * 4;   // global row (b*784+p)
        float s1 = 0.f, s2s = 0.f;
        int bsmp = 0, psmp = 0;
        if (EPI == 3) { bsmp = pbase / NPIX; psmp = pbase - bsmp * NPIX; }
        #pragma unroll
        for (int j = 0; j < 4; ++j) {
            const int oc = n0 + wn + j * 16 + col;
            if (EPI == 0) {
                float cb = bias[oc];
                #pragma unroll
                for (int r = 0; r < 4; ++r)
                    outh[(long)(pbase + r) * N + oc] = f2bf(acc[i][j][r] + cb);
            } else if (EPI == 1) {
                float sc = g[oc];
                float sh = bb[oc];
                #pragma unroll
                for (int r = 0; r < 4; ++r)
                    outh[(long)(pbase + r) * N + oc] =
                        f2bf(gelu_f(fmaf(acc[i][j][r], sc, sh)));
            } else if (EPI == 2) {
                float cb = bias[oc];
                #pragma unroll
                for (int r = 0; r < 4; ++r) {
                    long jj = (long)(pbase + r) * 256 + oc;
                    float val = acc[i][j][r] + cb + res[jj];
                    outf[jj] = val;
                    s1 += val; s2s += val * val;
                }
            } else {
                float sc = g[oc];
                float sh = bb[oc];
                long basei = ((long)bsmp * 256 + oc) * NPIX + psmp;
                float4 rv = *(const float4*)(res + basei);
                float4 y;
                y.x = fmaf(acc[i][j][0], sc, sh) + rv.x;
                y.y = fmaf(acc[i][j][1], sc, sh) + rv.y;
                y.z = fmaf(acc[i][j][2], sc, sh) + rv.z;
                y.w = fmaf(acc[i][j][3], sc, sh) + rv.w;
                *(float4*)(outf + basei) = y;
            }
        }
        if (EPI == 2) {
            #pragma unroll
            for (int o = 32; o > 0; o >>= 1) {
                s1 += __shfl_down(s1, o);
                s2s += __shfl_down(s2s, o);
            }
            if (lane == 0) {
                red[w * 4 + i][0] = (float)(pbase / NPIX);
                red[w * 4 + i][1] = s1;
                red[w * 4 + i][2] = s2s;
            }
        }
    }
    if (EPI == 2) {
        __syncthreads();
        if (t == 0) {
            int bsA = (int)red[0][0], bsB = -1;
            float a1 = 0.f, a2 = 0.f, b1 = 0.f, b2 = 0.f;
            #pragma unroll
            for (int e = 0; e < 16; ++e) {
                int bs = (int)red[e][0];
                if (bs == bsA) { a1 += red[e][1]; a2 += red[e][2]; }
                else           { bsB = bs; b1 += red[e][1]; b2 += red[e][2]; }
            }
            atomicAdd(&opart[bsA * 2], a1);
            atomicAdd(&opart[bsA * 2 + 1], a2);
            if (bsB >= 0) {
                atomicAdd(&opart[bsB * 2], b1);
                atomicAdd(&opart[bsB * 2 + 1], b2);
            }
        }
    }
}

// ---- MFMA flash attention v5: v3 structure (4 waves x 32 q-rows, proven
//      48.5us / coalesced writes) + per-kc pos_b PREFETCH: all 8 float4
//      loads issued before the MFMA+exp chain, so their HBM latency
//      overlaps (was serialized per (nt,i) step on the critical chain). ----
__global__ __launch_bounds__(256) void attn_kernel(const short* __restrict__ q,
                                                   const short* __restrict__ k,
                                                   const short* __restrict__ v,
                                                   const float* __restrict__ pos_b,
                                                   short* __restrict__ out) {
    __shared__ short Ks[208 * 40];   // [key][d], rows >=196 zero
    __shared__ short Vt[32 * 232];   // [d][key], cols 196..231 zero
    __shared__ float Ls[128];        // 1/rowsum per q
    const int qt0 = blockIdx.x * 128;
    const int h = blockIdx.y;
    const int b = blockIdx.z;
    const int t = threadIdx.x;
    const short8 z8 = {0, 0, 0, 0, 0, 0, 0, 0};
    // stage K (208 rows x 4 segs of 16B)
    for (int e = t; e < 832; e += 256) {
        int row = e >> 2, seg = e & 3;
        short8 v8 = (row < NKPIX)
            ? *(const short8*)(k + ((long)(b * NKPIX + row)) * 256 + h * 32 + seg * 8) : z8;
        *(short8*)(Ks + row * 40 + seg * 8) = v8;
    }
    // stage V transposed: vectorized global loads, b16 scatter into LDS
    for (int e = t; e < 784; e += 256) {
        int key = e >> 2, seg = e & 3;
        short8 tv = *(const short8*)(v + ((long)(b * NKPIX + key)) * 256 + h * 32 + seg * 8);
        #pragma unroll
        for (int j = 0; j < 8; ++j) Vt[(seg * 8 + j) * 232 + key] = tv[j];
    }
    // zero Vt pad cols 196..231
    for (int e = t; e < 32 * 36; e += 256) {
        Vt[(e / 36) * 232 + 196 + (e % 36)] = 0;
    }
    __syncthreads();

    const int w = t >> 6, lane = t & 63;
    const int col = lane & 15, quad = lane >> 4;
    const float scale = 0.17677669529663689f;
    const float4_ z4 = {0.f, 0.f, 0.f, 0.f};

    // Q fragments direct from global (B-operand rows = this wave's queries)
    short8 bq_[2];
    int qrow[2]; bool qvalid[2];
    const float* prow[2];
    #pragma unroll
    for (int i = 0; i < 2; ++i) {
        qrow[i] = qt0 + w * 32 + i * 16 + col;
        qvalid[i] = qrow[i] < NPIX;
        int qe = qvalid[i] ? qrow[i] : 0;
        bq_[i] = *(const short8*)(q + ((long)(b * NPIX + qe)) * 256 + h * 32 + quad * 8);
        prow[i] = pos_b + ((long)h * NPIX + qrow[i]) * NKPIX;
    }

    float4_ accO[2][2];
    #pragma unroll
    for (int i = 0; i < 2; ++i)
        #pragma unroll
        for (int nt = 0; nt < 2; ++nt) accO[i][nt] = z4;
    float lsum[2] = {0.f, 0.f};

    // redistribution source lanes (fixed per lane)
    const int srcA = col + 32 * (quad & 1);
    const int srcB = srcA + 16;
    const bool hihalf = quad >= 2;

    #pragma unroll
    for (int kc = 0; kc < 4; ++kc) {
        const int base = kc * 64;
        const int ntn = (kc == 3) ? 1 : 4;
        unsigned long long v64[2][4];
        if (kc == 3) { v64[0][1] = 0ULL; v64[1][1] = 0ULL; }
        // ---- pos_b prefetch: issue ALL loads for this kc up front so their
        //      HBM latency overlaps instead of sitting on the mfma->exp chain
        float4 pvv[4][2];
        #pragma unroll
        for (int nt = 0; nt < 4; ++nt) {
            if (nt >= ntn) continue;
            int keybase = base + nt * 16 + quad * 4;
            bool kval = keybase < NKPIX;
            #pragma unroll
            for (int i = 0; i < 2; ++i) {
                pvv[nt][i] = (kval && qvalid[i])
                    ? *(const float4*)(prow[i] + keybase)
                    : make_float4(0.f, 0.f, 0.f, 0.f);
            }
        }
        // ---- S^T pass: A = K-tile, B = Q-frag; P kept in registers ----
        #pragma unroll
        for (int nt = 0; nt < 4; ++nt) {
            if (nt >= ntn) continue;
            short8 afk = *(const short8*)(Ks + (base + nt * 16 + col) * 40 + quad * 8);
            int keybase = base + nt * 16 + quad * 4;
            bool kval = keybase < NKPIX;
            #pragma unroll
            for (int i = 0; i < 2; ++i) {
                float4_ s4 = __builtin_amdgcn_mfma_f32_16x16x32_bf16(afk, bq_[i], z4, 0, 0, 0);
                bool valid = kval && qvalid[i];
                float4 pv = pvv[nt][i];
                float p0 = valid ? __expf(s4[0] * scale + pv.x) : 0.f;
                float p1 = valid ? __expf(s4[1] * scale + pv.y) : 0.f;
                float p2 = valid ? __expf(s4[2] * scale + pv.z) : 0.f;
                float p3 = valid ? __expf(s4[3] * scale + pv.w) : 0.f;
                lsum[i] += p0 + p1 + p2 + p3;
                unsigned lo = ((unsigned)(unsigned short)f2bf(p1) << 16) |
                              (unsigned)(unsigned short)f2bf(p0);
                unsigned hi = ((unsigned)(unsigned short)f2bf(p3) << 16) |
                              (unsigned)(unsigned short)f2bf(p2);
                v64[i][nt] = ((unsigned long long)hi << 32) | lo;
            }
        }
        // ---- PV pass: assemble A-frag via 64-bit shuffles ----
        const int ksn = (kc == 3) ? 1 : 2;
        #pragma unroll
        for (int ks = 0; ks < 2; ++ks) {
            if (ks >= ksn) continue;
            #pragma unroll
            for (int i = 0; i < 2; ++i) {
                unsigned long long sel = hihalf ? v64[i][2 * ks + 1] : v64[i][2 * ks];
                unsigned long long flo = __shfl(sel, srcA, 64);
                unsigned long long fhi = __shfl(sel, srcB, 64);
                union { unsigned long long u; short s[4]; } ul, uh;
                ul.u = flo; uh.u = fhi;
                short8 afp = { ul.s[0], ul.s[1], ul.s[2], ul.s[3],
                               uh.s[0], uh.s[1], uh.s[2], uh.s[3] };
                #pragma unroll
                for (int nt = 0; nt < 2; ++nt) {
                    short8 bfv = *(const short8*)(Vt + (nt * 16 + col) * 232 + base + ks * 32 + quad * 8);
                    accO[i][nt] = __builtin_amdgcn_mfma_f32_16x16x32_bf16(afp, bfv, accO[i][nt], 0, 0, 0);
                }
            }
        }
    }
    // rowsum reduce across quads (lanes sharing col differ in bits 4..5)
    #pragma unroll
    for (int i = 0; i < 2; ++i) {
        float s = lsum[i];
        s += __shfl_xor(s, 16);
        s += __shfl_xor(s, 32);
        if (quad == 0) Ls[w * 32 + i * 16 + col] = 1.f / s;
    }
    __builtin_amdgcn_s_waitcnt(0);  // ensure own-wave Ls visible (same wave wrote it)
    // epilogue: O in C-layout (m = q = quad*4+r, n = d = nt*16+col)
    #pragma unroll
    for (int i = 0; i < 2; ++i) {
        int qb0 = qt0 + w * 32 + i * 16 + quad * 4;
        #pragma unroll
        for (int r = 0; r < 4; ++r) {
            int qq = qb0 + r;
            if (qq >= NPIX) continue;
            float rinv = Ls[w * 32 + i * 16 + quad * 4 + r];
            #pragma unroll
            for (int nt = 0; nt < 2; ++nt)
                out[((long)(b * NPIX + qq)) * 256 + h * 32 + nt * 16 + col] =
                    f2bf(accO[i][nt][r] * rinv);
        }
    }
}

// ---- dwconv3x3 + BN2 + GELU v3: 4 vertical pixels x 8 channels per thread ----
__global__ __launch_bounds__(256) void dwgelu_kernel(
    const short* __restrict__ t2, const float* __restrict__ wt,
    const float* __restrict__ sc2, const float* __restrict__ sh2,
    short* __restrict__ t3) {
    const int nchunk = 3136 / 8;   // blocks per XCD chunk
    int bid = blockIdx.x;
    int swz = (bid & 7) * nchunk + (bid >> 3);   // bijective (3136 % 8 == 0)
    int idx = swz * 256 + threadIdx.x;  // B*196*128 = 802,816
    int cm8 = idx & 127;
    int rest = idx >> 7;
    int grp = rest % 196;               // 7 y-groups x 28 columns
    int b = rest / 196;
    int py0 = (grp / 28) * 4;
    int px = grp % 28;
    int cm0 = cm8 * 8;
    const short* tb = t2 + ((long)b * NPIX) * CM + cm0;

    // weights: 9 taps x 8 channels, registers
    float wv[9][8];
    #pragma unroll
    for (int tp = 0; tp < 9; ++tp) {
        float4 a = *(const float4*)(wt + tp * 1024 + cm0);
        float4 bq = *(const float4*)(wt + tp * 1024 + cm0 + 4);
        wv[tp][0] = a.x;  wv[tp][1] = a.y;  wv[tp][2] = a.z;  wv[tp][3] = a.w;
        wv[tp][4] = bq.x; wv[tp][5] = bq.y; wv[tp][6] = bq.z; wv[tp][7] = bq.w;
    }

    float acc[4][8];
    #pragma unroll
    for (int k = 0; k < 4; ++k)
        #pragma unroll
        for (int c = 0; c < 8; ++c) acc[k][c] = 0.f;

    #pragma unroll
    for (int ro = -1; ro <= 4; ++ro) {
        int rr = py0 + ro;
        if (rr < 0 || rr >= H_) continue;
        const short* rowb = tb + (long)(rr * W_ + px) * CM;
        float fm[8], fc[8], fp[8];
        if (px > 0) {
            short8 s = *(const short8*)(rowb - CM);
            #pragma unroll
            for (int c = 0; c < 8; ++c) fm[c] = bf2f(s[c]);
        } else {
            #pragma unroll
            for (int c = 0; c < 8; ++c) fm[c] = 0.f;
        }
        {
            short8 s = *(const short8*)(rowb);
            #pragma unroll
            for (int c = 0; c < 8; ++c) fc[c] = bf2f(s[c]);
        }
        if (px < 27) {
            short8 s = *(const short8*)(rowb + CM);
            #pragma unroll
            for (int c = 0; c < 8; ++c) fp[c] = bf2f(s[c]);
        } else {
            #pragma unroll
            for (int c = 0; c < 8; ++c) fp[c] = 0.f;
        }
        #pragma unroll
        for (int k = 0; k < 4; ++k) {
            const int tr = ro - k + 1;     // tap row for output k (compile-time)
            if (tr < 0 || tr > 2) continue;
            #pragma unroll
            for (int c = 0; c < 8; ++c)
                acc[k][c] = fmaf(wv[tr * 3][c], fm[c],
                            fmaf(wv[tr * 3 + 1][c], fc[c],
                            fmaf(wv[tr * 3 + 2][c], fp[c], acc[k][c])));
        }
    }

    float4 sa = *(const float4*)(sc2 + cm0);
    float4 sb = *(const float4*)(sc2 + cm0 + 4);
    float4 ha = *(const float4*)(sh2 + cm0);
    float4 hb = *(const float4*)(sh2 + cm0 + 4);
    float scl[8] = {sa.x, sa.y, sa.z, sa.w, sb.x, sb.y, sb.z, sb.w};
    float shf[8] = {ha.x, ha.y, ha.z, ha.w, hb.x, hb.y, hb.z, hb.w};
    #pragma unroll
    for (int k = 0; k < 4; ++k) {
        short8 ov;
        #pragma unroll
        for (int c = 0; c < 8; ++c)
            ov[c] = f2bf(gelu_f(fmaf(acc[k][c], scl[c], shf[c])));
        *(short8*)(t3 + ((long)b * NPIX + (py0 + k) * W_ + px) * CM + cm0) = ov;
    }
}

extern "C" void kernel_launch(void* const* d_in, const int* in_sizes, int n_in,
                              void* d_out, int out_size, void* d_ws, size_t ws_size,
                              hipStream_t stream) {
    const float* x     = (const float*)d_in[0];
    const float* lpu_w = (const float*)d_in[1];
    const float* lpu_b = (const float*)d_in[2];
    const float* dw_w  = (const float*)d_in[3];
    const float* dw_b  = (const float*)d_in[4];
    const float* wq    = (const float*)d_in[5];
    const float* bq    = (const float*)d_in[6];
    const float* wk    = (const float*)d_in[7];
    const float* bk    = (const float*)d_in[8];
    const float* wv    = (const float*)d_in[9];
    const float* bv    = (const float*)d_in[10];
    const float* wo    = (const float*)d_in[11];
    const float* bo    = (const float*)d_in[12];
    const float* posb  = (const float*)d_in[13];
    const float* c1_w  = (const float*)d_in[14];
    const float* c1_b  = (const float*)d_in[15];
    const float* bn1_g = (const float*)d_in[16];
    const float* bn1_b = (const float*)d_in[17];
    const float* bn1_m = (const float*)d_in[18];
    const float* bn1_v = (const float*)d_in[19];
    const float* dw2_w = (const float*)d_in[20];
    const float* dw2_b = (const float*)d_in[21];
    const float* bn2_g = (const float*)d_in[22];
    const float* bn2_b = (const float*)d_in[23];
    const float* bn2_m = (const float*)d_in[24];
    const float* bn2_v = (const float*)d_in[25];
    const float* c2_w  = (const float*)d_in[26];
    const float* c2_b  = (const float*)d_in[27];
    const float* bn3_g = (const float*)d_in[28];
    const float* bn3_b = (const float*)d_in[29];
    const float* bn3_m = (const float*)d_in[30];
    const float* bn3_v = (const float*)d_in[31];

    const long n1  = (long)B_ * C_ * NPIX;    // 6,422,528
    const long nkv = (long)B_ * C_ * NKPIX;   // 1,605,632
    const long nm  = (long)B_ * CM * NPIX;    // 25,690,112
    const int  nblk1 = (int)(n1 / 1024);      // 6272 lpu blocks (196 per sample)
    const int  MQ = B_ * NPIX;                // 25088 = 196*128 (exact)
    const int  MKV = B_ * NKPIX;              // 6272  = 49*128  (exact)

    char* base = (char*)d_ws;
    float* x1   = (float*)base; base += n1 * 4;
    float* x2c  = (float*)base; base += n1 * 4;
    short* x1n  = (short*)base; base += n1 * 2;
    short* qb   = (short*)base; base += n1 * 2;
    short* tmpb = (short*)base; base += n1 * 2;
    short* t1n  = (short*)base; base += n1 * 2;
    short* kvb  = (short*)base; base += nkv * 2;
    short* kb   = (short*)base; base += nkv * 2;
    short* vb   = (short*)base; base += nkv * 2;
    short* t2   = (short*)base; base += nm * 2;
    short* t3   = (short*)base; base += nm * 2;
    short* wbf  = (short*)base; base += 786432L * 2;
    float* stats = (float*)base; base += 128 * 4;
    float* dwt   = (float*)base; base += 9216 * 4;   // [9][1024]
    float* dsc   = (float*)base; base += 1024 * 4;
    float* dsh   = (float*)base; base += 1024 * 4;
    float* dsc1  = (float*)base; base += 1024 * 4;
    float* dsh1  = (float*)base; base += 1024 * 4;
    float* dsc3  = (float*)base; base += 256 * 4;
    float* dsh3  = (float*)base; base += 256 * 4;
    float* part1 = (float*)base; base += (long)nblk1 * 2 * 4;
    float* outp = (float*)d_out;

    wconv_kernel<<<3072, 256, 0, stream>>>(wq, wk, wv, wo, c1_w, c2_w, wbf);
    dwprep_kernel<<<4, 256, 0, stream>>>(dw2_w, dw2_b, bn2_g, bn2_b, bn2_m, bn2_v,
                                         c1_b, bn1_g, bn1_b, bn1_m, bn1_v,
                                         c2_b, bn3_g, bn3_b, bn3_m, bn3_v,
                                         dwt, dsc, dsh, dsc1, dsh1, dsc3, dsh3,
                                         stats + 64);
    lpu_kernel<<<nblk1, 256, 0, stream>>>(x, lpu_w, lpu_b, x1, part1);
    lnreduce_kernel<<<B_, 256, 0, stream>>>(part1, nblk1 / B_, stats);
    kvconv_kernel<<<(int)((nkv + 255) / 256), 256, 0, stream>>>(x1, dw_w, dw_b, kvb);
    tln_kernel<<<dim3(25, 8, B_), 256, 0, stream>>>(x1, stats, x1n);
    // q projection: swizzled linear grid 392 = (196 i) x (2 j), j-fastest
    mfma_gemm<0, 1><<<392, 256, 0, stream>>>(
        x1n, wbf, MQ, 256, 256, bq, nullptr, nullptr,
        nullptr, nullptr, qb, nullptr);
    // k/v projections: 98 blocks (not %8) -> plain 2D grid
    mfma_gemm<0, 0><<<dim3(MKV / 128, 2), 256, 0, stream>>>(
        kvb, wbf + 65536, MKV, 256, 256, bk, nullptr, nullptr,
        nullptr, nullptr, kb, nullptr);
    mfma_gemm<0, 0><<<dim3(MKV / 128, 2), 256, 0, stream>>>(
        kvb, wbf + 131072, MKV, 256, 256, bv, nullptr, nullptr,
        nullptr, nullptr, vb, nullptr);
    attn_kernel<<<dim3(7, 8, B_), 256, 0, stream>>>(qb, kb, vb, posb, tmpb);
    // wo + flat residual + LN2 stats (swizzled 392)
    mfma_gemm<2, 1><<<392, 256, 0, stream>>>(
        tmpb, wbf + 196608, MQ, 256, 256, bo, nullptr, nullptr,
        x1, stats + 64, nullptr, x2c);
    tln_kernel<<<dim3(25, 8, B_), 256, 0, stream>>>(x2c, stats + 64, t1n);
    // conv1 1x1 + folded BN1 + fast GELU (swizzled 1568 = 196 x 8, j-fastest)
    mfma_gemm<1, 1><<<1568, 256, 0, stream>>>(
        t1n, wbf + 262144, MQ, CM, 256, nullptr, dsc1, dsh1,
        nullptr, nullptr, t2, nullptr);
    dwgelu_kernel<<<3136, 256, 0, stream>>>(t2, dwt, dsc, dsh, t3);
    // conv2 1x1 + folded BN3 + residual -> d_out (swizzled 392)
    mfma_gemm<3, 1><<<392, 256, 0, stream>>>(
        t3, wbf + 524288, MQ, 256, 1024, nullptr, dsc3, dsh3,
        x2c, nullptr, nullptr, outp);
}

// Round 14
// 392.875 us; speedup vs baseline: 1.0385x; 1.0308x over previous
//
#include <hip/hip_runtime.h>
#include <math.h>

#define B_ 32
#define C_ 256
#define H_ 28
#define W_ 28
#define NPIX 784
#define HK 14
#define NKPIX 196
#define CM 1024
#define EPS_ 1e-5f
#define LN_INVN (1.0f / (C_ * NPIX))

typedef __attribute__((ext_vector_type(8))) short short8;
typedef __attribute__((ext_vector_type(4))) short short4_;
typedef __attribute__((ext_vector_type(4))) float float4_;

// fast GELU: x*sigmoid(x*(2c + 2c*0.044715*x^2)), c=sqrt(2/pi) -- exact
// tanh-GELU identity. |err vs erf-GELU| <= ~1e-3, below bf16 quantization.
__device__ __forceinline__ float gelu_f(float x) {
    float u = x * fmaf(x * x, 0.0713548163f, 1.5957691216f);
    return x / (1.f + __expf(-u));
}
__device__ __forceinline__ short f2bf(float f) {
    union { float f; unsigned u; } x; x.f = f;
    unsigned r = x.u + 0x7FFF + ((x.u >> 16) & 1);
    return (short)(r >> 16);
}
__device__ __forceinline__ float bf2f(short s) {
    union { unsigned u; float f; } x; x.u = ((unsigned)(unsigned short)s) << 16;
    return x.f;
}
// async global->LDS, 16B per lane; LDS dest is wave-uniform base + lane*16
__device__ __forceinline__ void gld16(const short* g, short* l) {
    __builtin_amdgcn_global_load_lds((const __attribute__((address_space(1))) void*)g,
                                     (__attribute__((address_space(3))) void*)l,
                                     16, 0, 0);
}

// ---- convert all 6 weight matrices to bf16 (layout [oc][k], k contiguous) ----
__global__ void wconv_kernel(const float* __restrict__ wq, const float* __restrict__ wk,
                             const float* __restrict__ wv, const float* __restrict__ wo,
                             const float* __restrict__ c1, const float* __restrict__ c2,
                             short* __restrict__ dst) {
    int idx = blockIdx.x * 256 + threadIdx.x;  // total 786432
    const float* src; int off;
    if (idx < 65536)       { src = wq; off = idx; }
    else if (idx < 131072) { src = wk; off = idx - 65536; }
    else if (idx < 196608) { src = wv; off = idx - 131072; }
    else if (idx < 262144) { src = wo; off = idx - 196608; }
    else if (idx < 524288) { src = c1; off = idx - 262144; }
    else                   { src = c2; off = idx - 524288; }
    dst[idx] = f2bf(src[off]);
}

// ---- prep: dwgelu weights/BN2 fold; BN1+c1_b fold (sc1,sh1); BN3+c2_b fold
//      (sc3,sh3); zero the LN2 atomic-stat accumulator ----
__global__ void dwprep_kernel(const float* __restrict__ dww, const float* __restrict__ dwb,
                              const float* __restrict__ g2, const float* __restrict__ b2,
                              const float* __restrict__ m2, const float* __restrict__ v2,
                              const float* __restrict__ c1b, const float* __restrict__ g1,
                              const float* __restrict__ b1, const float* __restrict__ m1,
                              const float* __restrict__ v1,
                              const float* __restrict__ c2b, const float* __restrict__ g3,
                              const float* __restrict__ b3, const float* __restrict__ m3,
                              const float* __restrict__ v3,
                              float* __restrict__ wt, float* __restrict__ sc2,
                              float* __restrict__ sh2, float* __restrict__ sc1,
                              float* __restrict__ sh1, float* __restrict__ sc3,
                              float* __restrict__ sh3, float* __restrict__ st2) {
    int cm = blockIdx.x * 256 + threadIdx.x;  // 1024
    if (blockIdx.x == 0 && threadIdx.x < 64) st2[threadIdx.x] = 0.f;
    float sc = g2[cm] * rsqrtf(v2[cm] + EPS_);
    sc2[cm] = sc;
    sh2[cm] = (dwb[cm] - m2[cm]) * sc + b2[cm];
    float s1 = g1[cm] * rsqrtf(v1[cm] + EPS_);
    sc1[cm] = s1;
    sh1[cm] = (c1b[cm] - m1[cm]) * s1 + b1[cm];
    if (cm < 256) {
        float s3 = g3[cm] * rsqrtf(v3[cm] + EPS_);
        sc3[cm] = s3;
        sh3[cm] = (c2b[cm] - m3[cm]) * s3 + b3[cm];
    }
    #pragma unroll
    for (int tap = 0; tap < 9; ++tap) wt[tap * 1024 + cm] = dww[cm * 9 + tap];
}

// ---- generic LN stats reduce: 32 blocks, each folds cnt (sum,sumsq) pairs ----
__global__ void lnreduce_kernel(const float* __restrict__ part, int cnt,
                                float* __restrict__ out) {
    int b = blockIdx.x;
    const float* p = part + (long)b * cnt * 2;
    float s = 0.f, s2 = 0.f;
    for (int i = threadIdx.x; i < cnt; i += 256) {
        s += p[i * 2];
        s2 += p[i * 2 + 1];
    }
    #pragma unroll
    for (int o = 32; o > 0; o >>= 1) {
        s += __shfl_down(s, o);
        s2 += __shfl_down(s2, o);
    }
    __shared__ float ss[4][2];
    int wv = threadIdx.x >> 6;
    if ((threadIdx.x & 63) == 0) { ss[wv][0] = s; ss[wv][1] = s2; }
    __syncthreads();
    if (threadIdx.x == 0) {
        out[b * 2]     = ss[0][0] + ss[1][0] + ss[2][0] + ss[3][0];
        out[b * 2 + 1] = ss[0][1] + ss[1][1] + ss[2][1] + ss[3][1];
    }
}

// ---- LPU v2: depthwise 3x3 + bias + residual, 4 pixels/thread (float4) ----
__global__ void lpu_kernel(const float* __restrict__ x, const float* __restrict__ w,
                           const float* __restrict__ bias, float* __restrict__ out,
                           float* __restrict__ part) {
    int idx4 = blockIdx.x * 256 + threadIdx.x;   // B*C*196 = 1,605,632 chunks
    int chunk = idx4 % 196;
    int plane = idx4 / 196;                      // b*256 + c
    int c = plane & 255;
    int p0 = chunk * 4;
    int py = p0 / W_, px0 = p0 % W_;             // px0 in {0,4,...,24}
    const float* xp = x + (long)plane * NPIX;
    const float* wc = w + c * 9;
    float4 cc = *(const float4*)(xp + py * W_ + px0);
    float bb = bias[c];
    float acc0 = bb + cc.x, acc1 = bb + cc.y, acc2 = bb + cc.z, acc3 = bb + cc.w;
    #pragma unroll
    for (int dy = -1; dy <= 1; ++dy) {
        int yy = py + dy;
        if (yy < 0 || yy >= H_) continue;
        float4 v = (dy == 0) ? cc : *(const float4*)(xp + yy * W_ + px0);
        float vm1 = (px0 > 0)  ? xp[yy * W_ + px0 - 1] : 0.f;
        float v4  = (px0 < 24) ? xp[yy * W_ + px0 + 4] : 0.f;
        float w0 = wc[(dy + 1) * 3], w1 = wc[(dy + 1) * 3 + 1], w2 = wc[(dy + 1) * 3 + 2];
        acc0 += w0 * vm1 + w1 * v.x + w2 * v.y;
        acc1 += w0 * v.x + w1 * v.y + w2 * v.z;
        acc2 += w0 * v.y + w1 * v.z + w2 * v.w;
        acc3 += w0 * v.z + w1 * v.w + w2 * v4;
    }
    *(float4*)(out + (long)plane * NPIX + p0) = make_float4(acc0, acc1, acc2, acc3);
    float s = acc0 + acc1 + acc2 + acc3;
    float s2 = acc0 * acc0 + acc1 * acc1 + acc2 * acc2 + acc3 * acc3;
    #pragma unroll
    for (int o = 32; o > 0; o >>= 1) {
        s += __shfl_down(s, o);
        s2 += __shfl_down(s2, o);
    }
    __shared__ float ss[4][2];
    int wv = threadIdx.x >> 6;
    if ((threadIdx.x & 63) == 0) { ss[wv][0] = s; ss[wv][1] = s2; }
    __syncthreads();
    if (threadIdx.x == 0) {
        part[blockIdx.x * 2]     = ss[0][0] + ss[1][0] + ss[2][0] + ss[3][0];
        part[blockIdx.x * 2 + 1] = ss[0][1] + ss[1][1] + ss[2][1] + ss[3][1];
    }
}

// ---- transpose + LayerNorm: fp32 [b][256][784] -> bf16 [b][784][256] ----
__global__ void tln_kernel(const float* __restrict__ X, const float* __restrict__ st,
                           short* __restrict__ Y) {
    __shared__ float tile[32][33];
    int p0 = blockIdx.x * 32, c0 = blockIdx.y * 32, b = blockIdx.z;
    int tr = threadIdx.x >> 5, tc = threadIdx.x & 31;
    #pragma unroll
    for (int r = 0; r < 4; ++r) {
        int c = c0 + tr + r * 8, p = p0 + tc;
        tile[tr + r * 8][tc] = (p < NPIX) ? X[((long)b * C_ + c) * NPIX + p] : 0.f;
    }
    float sm = st[b * 2] * LN_INVN;
    float lr = rsqrtf(st[b * 2 + 1] * LN_INVN - sm * sm + EPS_);
    __syncthreads();
    #pragma unroll
    for (int r = 0; r < 4; ++r) {
        int p = p0 + tr + r * 8, c = c0 + tc;
        if (p < NPIX) Y[((long)b * NPIX + p) * C_ + c] = f2bf((tile[tc][tr + r * 8] - sm) * lr);
    }
}

// ---- kv depthwise 2x2 stride-2 (x1 fp32 channel-major -> bf16 pixel-major) ----
__global__ void kvconv_kernel(const float* __restrict__ x1, const float* __restrict__ w,
                              const float* __restrict__ bias, short* __restrict__ out) {
    int idx = blockIdx.x * 256 + threadIdx.x;
    if (idx >= B_ * NKPIX * C_) return;
    int c = idx & 255;
    int rest = idx >> 8;
    int p = rest % NKPIX;
    int b = rest / NKPIX;
    int yo = p / HK, xo = p % HK;
    const float* xb = x1 + ((long)b * C_ + c) * NPIX;
    const float* wc = w + c * 4;
    float a = bias[c]
            + wc[0] * xb[(2 * yo) * W_ + 2 * xo]     + wc[1] * xb[(2 * yo) * W_ + 2 * xo + 1]
            + wc[2] * xb[(2 * yo + 1) * W_ + 2 * xo] + wc[3] * xb[(2 * yo + 1) * W_ + 2 * xo + 1];
    out[idx] = f2bf(a);
}

// ---- MFMA GEMM, batch-merged M, 2-phase double-buffered global_load_lds.
//      SWZ=1: linear grid, XCD-chunked + j-FASTEST decode.
//      __launch_bounds__(256, 4): cap total regs at 128 (64 AGPR acc + 64
//      arch) -> 4 waves/SIMD -> 4 blocks/CU (was 152 regs -> 3 waves, 18%
//      occupancy, 65% idle). K-loop working set ~96 regs fits; only
//      epilogue temps get squeezed. Guardrail: spill shows as WRITE_SIZE
//      inflation (round-5 signature). ----
template <int EPI, int SWZ>
__global__ __launch_bounds__(256, 4) void mfma_gemm(
    const short* __restrict__ Act, const short* __restrict__ Wb,
    int M, int N, int K,
    const float* __restrict__ bias,
    const float* __restrict__ g, const float* __restrict__ bb,
    const float* __restrict__ res, float* __restrict__ opart,
    short* __restrict__ outh, float* __restrict__ outf) {
    __shared__ short As[2 * 128 * 32];
    __shared__ short Bs[2 * 128 * 32];
    __shared__ float red[16][3];
    const int t = threadIdx.x;
    int ix, jy;
    if (SWZ) {
        const int nwg = gridDim.x;          // multiple of 8
        const int chunk = nwg >> 3;
        const int swz = (blockIdx.x & 7) * chunk + (blockIdx.x >> 3);
        const int ny = N >> 7;              // power of two (2 or 8)
        jy = swz & (ny - 1);
        ix = swz / ny;
    } else {
        ix = blockIdx.x; jy = blockIdx.y;
    }
    const int m0 = ix * 128;
    const int n0 = jy * 128;
    const int w = t >> 6, lane = t & 63;
    const int wm = (w & 1) * 64, wn = (w >> 1) * 64;
    const int col = lane & 15, quad = lane >> 4;

    float4_ acc[4][4];
    #pragma unroll
    for (int i = 0; i < 4; ++i)
        #pragma unroll
        for (int j = 0; j < 4; ++j)
            acc[i][j] = (float4_){0.f, 0.f, 0.f, 0.f};

    const int l4 = lane >> 2;
    const int segsw = (lane & 3) ^ ((l4 ^ (l4 >> 2)) & 3);
    const short* gA = Act + (long)(m0 + w * 16 + l4) * K + segsw * 8;
    const short* gB = Wb  + (long)(n0 + w * 16 + l4) * K + segsw * 8;
    const long rs64 = (long)64 * K;
    const int woff = w * 512;   // w*16 rows * 32 shorts

    const int nk = K >> 5;
    {
        short* dA = As + woff;
        short* dB = Bs + woff;
        gld16(gA, dA);
        gld16(gA + rs64, dA + 2048);
        gld16(gB, dB);
        gld16(gB + rs64, dB + 2048);
    }
    const int slotsw = (quad ^ ((col & 3) ^ ((col >> 2) & 3))) * 8;

    for (int kt = 0; kt < nk; ++kt) {
        __syncthreads();   // buf[kt&1] staged (vmcnt drained); prev reads done
        const int cur = (kt & 1) * 4096;
        if (kt + 1 < nk) {
            const int nxtoff = ((kt + 1) & 1) * 4096 + woff;
            const int k0 = (kt + 1) * 32;
            gld16(gA + k0, As + nxtoff);
            gld16(gA + rs64 + k0, As + nxtoff + 2048);
            gld16(gB + k0, Bs + nxtoff);
            gld16(gB + rs64 + k0, Bs + nxtoff + 2048);
        }
        short8 af[4], bf[4];
        #pragma unroll
        for (int i = 0; i < 4; ++i)
            af[i] = *(const short8*)(As + cur + (wm + i * 16 + col) * 32 + slotsw);
        #pragma unroll
        for (int j = 0; j < 4; ++j)
            bf[j] = *(const short8*)(Bs + cur + (wn + j * 16 + col) * 32 + slotsw);
        #pragma unroll
        for (int i = 0; i < 4; ++i)
            #pragma unroll
            for (int j = 0; j < 4; ++j)
                acc[i][j] = __builtin_amdgcn_mfma_f32_16x16x32_bf16(af[i], bf[j], acc[i][j], 0, 0, 0);
    }

    #pragma unroll
    for (int i = 0; i < 4; ++i) {
        const int pbase = m0 + wm + i * 16 + quad * 4;   // global row (b*784+p)
        float s1 = 0.f, s2s = 0.f;
        int bsmp = 0, psmp = 0;
        if (EPI == 3) { bsmp = pbase / NPIX; psmp = pbase - bsmp * NPIX; }
        #pragma unroll
        for (int j = 0; j < 4; ++j) {
            const int oc = n0 + wn + j * 16 + col;
            if (EPI == 0) {
                float cb = bias[oc];
                #pragma unroll
                for (int r = 0; r < 4; ++r)
                    outh[(long)(pbase + r) * N + oc] = f2bf(acc[i][j][r] + cb);
            } else if (EPI == 1) {
                float sc = g[oc];
                float sh = bb[oc];
                #pragma unroll
                for (int r = 0; r < 4; ++r)
                    outh[(long)(pbase + r) * N + oc] =
                        f2bf(gelu_f(fmaf(acc[i][j][r], sc, sh)));
            } else if (EPI == 2) {
                float cb = bias[oc];
                #pragma unroll
                for (int r = 0; r < 4; ++r) {
                    long jj = (long)(pbase + r) * 256 + oc;
                    float val = acc[i][j][r] + cb + res[jj];
                    outf[jj] = val;
                    s1 += val; s2s += val * val;
                }
            } else {
                float sc = g[oc];
                float sh = bb[oc];
                long basei = ((long)bsmp * 256 + oc) * NPIX + psmp;
                float4 rv = *(const float4*)(res + basei);
                float4 y;
                y.x = fmaf(acc[i][j][0], sc, sh) + rv.x;
                y.y = fmaf(acc[i][j][1], sc, sh) + rv.y;
                y.z = fmaf(acc[i][j][2], sc, sh) + rv.z;
                y.w = fmaf(acc[i][j][3], sc, sh) + rv.w;
                *(float4*)(outf + basei) = y;
            }
        }
        if (EPI == 2) {
            #pragma unroll
            for (int o = 32; o > 0; o >>= 1) {
                s1 += __shfl_down(s1, o);
                s2s += __shfl_down(s2s, o);
            }
            if (lane == 0) {
                red[w * 4 + i][0] = (float)(pbase / NPIX);
                red[w * 4 + i][1] = s1;
                red[w * 4 + i][2] = s2s;
            }
        }
    }
    if (EPI == 2) {
        __syncthreads();
        if (t == 0) {
            int bsA = (int)red[0][0], bsB = -1;
            float a1 = 0.f, a2 = 0.f, b1 = 0.f, b2 = 0.f;
            #pragma unroll
            for (int e = 0; e < 16; ++e) {
                int bs = (int)red[e][0];
                if (bs == bsA) { a1 += red[e][1]; a2 += red[e][2]; }
                else           { bsB = bs; b1 += red[e][1]; b2 += red[e][2]; }
            }
            atomicAdd(&opart[bsA * 2], a1);
            atomicAdd(&opart[bsA * 2 + 1], a2);
            if (bsB >= 0) {
                atomicAdd(&opart[bsB * 2], b1);
                atomicAdd(&opart[bsB * 2 + 1], b2);
            }
        }
    }
}

// ---- MFMA flash attention v5: v3 structure + per-kc pos_b prefetch ----
__global__ __launch_bounds__(256) void attn_kernel(const short* __restrict__ q,
                                                   const short* __restrict__ k,
                                                   const short* __restrict__ v,
                                                   const float* __restrict__ pos_b,
                                                   short* __restrict__ out) {
    __shared__ short Ks[208 * 40];   // [key][d], rows >=196 zero
    __shared__ short Vt[32 * 232];   // [d][key], cols 196..231 zero
    __shared__ float Ls[128];        // 1/rowsum per q
    const int qt0 = blockIdx.x * 128;
    const int h = blockIdx.y;
    const int b = blockIdx.z;
    const int t = threadIdx.x;
    const short8 z8 = {0, 0, 0, 0, 0, 0, 0, 0};
    // stage K (208 rows x 4 segs of 16B)
    for (int e = t; e < 832; e += 256) {
        int row = e >> 2, seg = e & 3;
        short8 v8 = (row < NKPIX)
            ? *(const short8*)(k + ((long)(b * NKPIX + row)) * 256 + h * 32 + seg * 8) : z8;
        *(short8*)(Ks + row * 40 + seg * 8) = v8;
    }
    // stage V transposed: vectorized global loads, b16 scatter into LDS
    for (int e = t; e < 784; e += 256) {
        int key = e >> 2, seg = e & 3;
        short8 tv = *(const short8*)(v + ((long)(b * NKPIX + key)) * 256 + h * 32 + seg * 8);
        #pragma unroll
        for (int j = 0; j < 8; ++j) Vt[(seg * 8 + j) * 232 + key] = tv[j];
    }
    // zero Vt pad cols 196..231
    for (int e = t; e < 32 * 36; e += 256) {
        Vt[(e / 36) * 232 + 196 + (e % 36)] = 0;
    }
    __syncthreads();

    const int w = t >> 6, lane = t & 63;
    const int col = lane & 15, quad = lane >> 4;
    const float scale = 0.17677669529663689f;
    const float4_ z4 = {0.f, 0.f, 0.f, 0.f};

    // Q fragments direct from global (B-operand rows = this wave's queries)
    short8 bq_[2];
    int qrow[2]; bool qvalid[2];
    const float* prow[2];
    #pragma unroll
    for (int i = 0; i < 2; ++i) {
        qrow[i] = qt0 + w * 32 + i * 16 + col;
        qvalid[i] = qrow[i] < NPIX;
        int qe = qvalid[i] ? qrow[i] : 0;
        bq_[i] = *(const short8*)(q + ((long)(b * NPIX + qe)) * 256 + h * 32 + quad * 8);
        prow[i] = pos_b + ((long)h * NPIX + qrow[i]) * NKPIX;
    }

    float4_ accO[2][2];
    #pragma unroll
    for (int i = 0; i < 2; ++i)
        #pragma unroll
        for (int nt = 0; nt < 2; ++nt) accO[i][nt] = z4;
    float lsum[2] = {0.f, 0.f};

    // redistribution source lanes (fixed per lane)
    const int srcA = col + 32 * (quad & 1);
    const int srcB = srcA + 16;
    const bool hihalf = quad >= 2;

    #pragma unroll
    for (int kc = 0; kc < 4; ++kc) {
        const int base = kc * 64;
        const int ntn = (kc == 3) ? 1 : 4;
        unsigned long long v64[2][4];
        if (kc == 3) { v64[0][1] = 0ULL; v64[1][1] = 0ULL; }
        // ---- pos_b prefetch: issue ALL loads for this kc up front so their
        //      HBM latency overlaps instead of sitting on the mfma->exp chain
        float4 pvv[4][2];
        #pragma unroll
        for (int nt = 0; nt < 4; ++nt) {
            if (nt >= ntn) continue;
            int keybase = base + nt * 16 + quad * 4;
            bool kval = keybase < NKPIX;
            #pragma unroll
            for (int i = 0; i < 2; ++i) {
                pvv[nt][i] = (kval && qvalid[i])
                    ? *(const float4*)(prow[i] + keybase)
                    : make_float4(0.f, 0.f, 0.f, 0.f);
            }
        }
        // ---- S^T pass: A = K-tile, B = Q-frag; P kept in registers ----
        #pragma unroll
        for (int nt = 0; nt < 4; ++nt) {
            if (nt >= ntn) continue;
            short8 afk = *(const short8*)(Ks + (base + nt * 16 + col) * 40 + quad * 8);
            int keybase = base + nt * 16 + quad * 4;
            bool kval = keybase < NKPIX;
            #pragma unroll
            for (int i = 0; i < 2; ++i) {
                float4_ s4 = __builtin_amdgcn_mfma_f32_16x16x32_bf16(afk, bq_[i], z4, 0, 0, 0);
                bool valid = kval && qvalid[i];
                float4 pv = pvv[nt][i];
                float p0 = valid ? __expf(s4[0] * scale + pv.x) : 0.f;
                float p1 = valid ? __expf(s4[1] * scale + pv.y) : 0.f;
                float p2 = valid ? __expf(s4[2] * scale + pv.z) : 0.f;
                float p3 = valid ? __expf(s4[3] * scale + pv.w) : 0.f;
                lsum[i] += p0 + p1 + p2 + p3;
                unsigned lo = ((unsigned)(unsigned short)f2bf(p1) << 16) |
                              (unsigned)(unsigned short)f2bf(p0);
                unsigned hi = ((unsigned)(unsigned short)f2bf(p3) << 16) |
                              (unsigned)(unsigned short)f2bf(p2);
                v64[i][nt] = ((unsigned long long)hi << 32) | lo;
            }
        }
        // ---- PV pass: assemble A-frag via 64-bit shuffles ----
        const int ksn = (kc == 3) ? 1 : 2;
        #pragma unroll
        for (int ks = 0; ks < 2; ++ks) {
            if (ks >= ksn) continue;
            #pragma unroll
            for (int i = 0; i < 2; ++i) {
                unsigned long long sel = hihalf ? v64[i][2 * ks + 1] : v64[i][2 * ks];
                unsigned long long flo = __shfl(sel, srcA, 64);
                unsigned long long fhi = __shfl(sel, srcB, 64);
                union { unsigned long long u; short s[4]; } ul, uh;
                ul.u = flo; uh.u = fhi;
                short8 afp = { ul.s[0], ul.s[1], ul.s[2], ul.s[3],
                               uh.s[0], uh.s[1], uh.s[2], uh.s[3] };
                #pragma unroll
                for (int nt = 0; nt < 2; ++nt) {
                    short8 bfv = *(const short8*)(Vt + (nt * 16 + col) * 232 + base + ks * 32 + quad * 8);
                    accO[i][nt] = __builtin_amdgcn_mfma_f32_16x16x32_bf16(afp, bfv, accO[i][nt], 0, 0, 0);
                }
            }
        }
    }
    // rowsum reduce across quads (lanes sharing col differ in bits 4..5)
    #pragma unroll
    for (int i = 0; i < 2; ++i) {
        float s = lsum[i];
        s += __shfl_xor(s, 16);
        s += __shfl_xor(s, 32);
        if (quad == 0) Ls[w * 32 + i * 16 + col] = 1.f / s;
    }
    __builtin_amdgcn_s_waitcnt(0);  // ensure own-wave Ls visible (same wave wrote it)
    // epilogue: O in C-layout (m = q = quad*4+r, n = d = nt*16+col)
    #pragma unroll
    for (int i = 0; i < 2; ++i) {
        int qb0 = qt0 + w * 32 + i * 16 + quad * 4;
        #pragma unroll
        for (int r = 0; r < 4; ++r) {
            int qq = qb0 + r;
            if (qq >= NPIX) continue;
            float rinv = Ls[w * 32 + i * 16 + quad * 4 + r];
            #pragma unroll
            for (int nt = 0; nt < 2; ++nt)
                out[((long)(b * NPIX + qq)) * 256 + h * 32 + nt * 16 + col] =
                    f2bf(accO[i][nt][r] * rinv);
        }
    }
}

// ---- dwconv3x3 + BN2 + GELU v3: 4 vertical pixels x 8 channels per thread ----
__global__ __launch_bounds__(256) void dwgelu_kernel(
    const short* __restrict__ t2, const float* __restrict__ wt,
    const float* __restrict__ sc2, const float* __restrict__ sh2,
    short* __restrict__ t3) {
    const int nchunk = 3136 / 8;   // blocks per XCD chunk
    int bid = blockIdx.x;
    int swz = (bid & 7) * nchunk + (bid >> 3);   // bijective (3136 % 8 == 0)
    int idx = swz * 256 + threadIdx.x;  // B*196*128 = 802,816
    int cm8 = idx & 127;
    int rest = idx >> 7;
    int grp = rest % 196;               // 7 y-groups x 28 columns
    int b = rest / 196;
    int py0 = (grp / 28) * 4;
    int px = grp % 28;
    int cm0 = cm8 * 8;
    const short* tb = t2 + ((long)b * NPIX) * CM + cm0;

    // weights: 9 taps x 8 channels, registers
    float wv[9][8];
    #pragma unroll
    for (int tp = 0; tp < 9; ++tp) {
        float4 a = *(const float4*)(wt + tp * 1024 + cm0);
        float4 bq = *(const float4*)(wt + tp * 1024 + cm0 + 4);
        wv[tp][0] = a.x;  wv[tp][1] = a.y;  wv[tp][2] = a.z;  wv[tp][3] = a.w;
        wv[tp][4] = bq.x; wv[tp][5] = bq.y; wv[tp][6] = bq.z; wv[tp][7] = bq.w;
    }

    float acc[4][8];
    #pragma unroll
    for (int k = 0; k < 4; ++k)
        #pragma unroll
        for (int c = 0; c < 8; ++c) acc[k][c] = 0.f;

    #pragma unroll
    for (int ro = -1; ro <= 4; ++ro) {
        int rr = py0 + ro;
        if (rr < 0 || rr >= H_) continue;
        const short* rowb = tb + (long)(rr * W_ + px) * CM;
        float fm[8], fc[8], fp[8];
        if (px > 0) {
            short8 s = *(const short8*)(rowb - CM);
            #pragma unroll
            for (int c = 0; c < 8; ++c) fm[c] = bf2f(s[c]);
        } else {
            #pragma unroll
            for (int c = 0; c < 8; ++c) fm[c] = 0.f;
        }
        {
            short8 s = *(const short8*)(rowb);
            #pragma unroll
            for (int c = 0; c < 8; ++c) fc[c] = bf2f(s[c]);
        }
        if (px < 27) {
            short8 s = *(const short8*)(rowb + CM);
            #pragma unroll
            for (int c = 0; c < 8; ++c) fp[c] = bf2f(s[c]);
        } else {
            #pragma unroll
            for (int c = 0; c < 8; ++c) fp[c] = 0.f;
        }
        #pragma unroll
        for (int k = 0; k < 4; ++k) {
            const int tr = ro - k + 1;     // tap row for output k (compile-time)
            if (tr < 0 || tr > 2) continue;
            #pragma unroll
            for (int c = 0; c < 8; ++c)
                acc[k][c] = fmaf(wv[tr * 3][c], fm[c],
                            fmaf(wv[tr * 3 + 1][c], fc[c],
                            fmaf(wv[tr * 3 + 2][c], fp[c], acc[k][c])));
        }
    }

    float4 sa = *(const float4*)(sc2 + cm0);
    float4 sb = *(const float4*)(sc2 + cm0 + 4);
    float4 ha = *(const float4*)(sh2 + cm0);
    float4 hb = *(const float4*)(sh2 + cm0 + 4);
    float scl[8] = {sa.x, sa.y, sa.z, sa.w, sb.x, sb.y, sb.z, sb.w};
    float shf[8] = {ha.x, ha.y, ha.z, ha.w, hb.x, hb.y, hb.z, hb.w};
    #pragma unroll
    for (int k = 0; k < 4; ++k) {
        short8 ov;
        #pragma unroll
        for (int c = 0; c < 8; ++c)
            ov[c] = f2bf(gelu_f(fmaf(acc[k][c], scl[c], shf[c])));
        *(short8*)(t3 + ((long)b * NPIX + (py0 + k) * W_ + px) * CM + cm0) = ov;
    }
}

extern "C" void kernel_launch(void* const* d_in, const int* in_sizes, int n_in,
                              void* d_out, int out_size, void* d_ws, size_t ws_size,
                              hipStream_t stream) {
    const float* x     = (const float*)d_in[0];
    const float* lpu_w = (const float*)d_in[1];
    const float* lpu_b = (const float*)d_in[2];
    const float* dw_w  = (const float*)d_in[3];
    const float* dw_b  = (const float*)d_in[4];
    const float* wq    = (const float*)d_in[5];
    const float* bq    = (const float*)d_in[6];
    const float* wk    = (const float*)d_in[7];
    const float* bk    = (const float*)d_in[8];
    const float* wv    = (const float*)d_in[9];
    const float* bv    = (const float*)d_in[10];
    const float* wo    = (const float*)d_in[11];
    const float* bo    = (const float*)d_in[12];
    const float* posb  = (const float*)d_in[13];
    const float* c1_w  = (const float*)d_in[14];
    const float* c1_b  = (const float*)d_in[15];
    const float* bn1_g = (const float*)d_in[16];
    const float* bn1_b = (const float*)d_in[17];
    const float* bn1_m = (const float*)d_in[18];
    const float* bn1_v = (const float*)d_in[19];
    const float* dw2_w = (const float*)d_in[20];
    const float* dw2_b = (const float*)d_in[21];
    const float* bn2_g = (const float*)d_in[22];
    const float* bn2_b = (const float*)d_in[23];
    const float* bn2_m = (const float*)d_in[24];
    const float* bn2_v = (const float*)d_in[25];
    const float* c2_w  = (const float*)d_in[26];
    const float* c2_b  = (const float*)d_in[27];
    const float* bn3_g = (const float*)d_in[28];
    const float* bn3_b = (const float*)d_in[29];
    const float* bn3_m = (const float*)d_in[30];
    const float* bn3_v = (const float*)d_in[31];

    const long n1  = (long)B_ * C_ * NPIX;    // 6,422,528
    const long nkv = (long)B_ * C_ * NKPIX;   // 1,605,632
    const long nm  = (long)B_ * CM * NPIX;    // 25,690,112
    const int  nblk1 = (int)(n1 / 1024);      // 6272 lpu blocks (196 per sample)
    const int  MQ = B_ * NPIX;                // 25088 = 196*128 (exact)
    const int  MKV = B_ * NKPIX;              // 6272  = 49*128  (exact)

    char* base = (char*)d_ws;
    float* x1   = (float*)base; base += n1 * 4;
    float* x2c  = (float*)base; base += n1 * 4;
    short* x1n  = (short*)base; base += n1 * 2;
    short* qb   = (short*)base; base += n1 * 2;
    short* tmpb = (short*)base; base += n1 * 2;
    short* t1n  = (short*)base; base += n1 * 2;
    short* kvb  = (short*)base; base += nkv * 2;
    short* kb   = (short*)base; base += nkv * 2;
    short* vb   = (short*)base; base += nkv * 2;
    short* t2   = (short*)base; base += nm * 2;
    short* t3   = (short*)base; base += nm * 2;
    short* wbf  = (short*)base; base += 786432L * 2;
    float* stats = (float*)base; base += 128 * 4;
    float* dwt   = (float*)base; base += 9216 * 4;   // [9][1024]
    float* dsc   = (float*)base; base += 1024 * 4;
    float* dsh   = (float*)base; base += 1024 * 4;
    float* dsc1  = (float*)base; base += 1024 * 4;
    float* dsh1  = (float*)base; base += 1024 * 4;
    float* dsc3  = (float*)base; base += 256 * 4;
    float* dsh3  = (float*)base; base += 256 * 4;
    float* part1 = (float*)base; base += (long)nblk1 * 2 * 4;
    float* outp = (float*)d_out;

    wconv_kernel<<<3072, 256, 0, stream>>>(wq, wk, wv, wo, c1_w, c2_w, wbf);
    dwprep_kernel<<<4, 256, 0, stream>>>(dw2_w, dw2_b, bn2_g, bn2_b, bn2_m, bn2_v,
                                         c1_b, bn1_g, bn1_b, bn1_m, bn1_v,
                                         c2_b, bn3_g, bn3_b, bn3_m, bn3_v,
                                         dwt, dsc, dsh, dsc1, dsh1, dsc3, dsh3,
                                         stats + 64);
    lpu_kernel<<<nblk1, 256, 0, stream>>>(x, lpu_w, lpu_b, x1, part1);
    lnreduce_kernel<<<B_, 256, 0, stream>>>(part1, nblk1 / B_, stats);
    kvconv_kernel<<<(int)((nkv + 255) / 256), 256, 0, stream>>>(x1, dw_w, dw_b, kvb);
    tln_kernel<<<dim3(25, 8, B_), 256, 0, stream>>>(x1, stats, x1n);
    // q projection: swizzled linear grid 392 = (196 i) x (2 j), j-fastest
    mfma_gemm<0, 1><<<392, 256, 0, stream>>>(
        x1n, wbf, MQ, 256, 256, bq, nullptr, nullptr,
        nullptr, nullptr, qb, nullptr);
    // k/v projections: 98 blocks (not %8) -> plain 2D grid
    mfma_gemm<0, 0><<<dim3(MKV / 128, 2), 256, 0, stream>>>(
        kvb, wbf + 65536, MKV, 256, 256, bk, nullptr, nullptr,
        nullptr, nullptr, kb, nullptr);
    mfma_gemm<0, 0><<<dim3(MKV / 128, 2), 256, 0, stream>>>(
        kvb, wbf + 131072, MKV, 256, 256, bv, nullptr, nullptr,
        nullptr, nullptr, vb, nullptr);
    attn_kernel<<<dim3(7, 8, B_), 256, 0, stream>>>(qb, kb, vb, posb, tmpb);
    // wo + flat residual + LN2 stats (swizzled 392)
    mfma_gemm<2, 1><<<392, 256, 0, stream>>>(
        tmpb, wbf + 196608, MQ, 256, 256, bo, nullptr, nullptr,
        x1, stats + 64, nullptr, x2c);
    tln_kernel<<<dim3(25, 8, B_), 256, 0, stream>>>(x2c, stats + 64, t1n);
    // conv1 1x1 + folded BN1 + fast GELU (swizzled 1568 = 196 x 8, j-fastest)
    mfma_gemm<1, 1><<<1568, 256, 0, stream>>>(
        t1n, wbf + 262144, MQ, CM, 256, nullptr, dsc1, dsh1,
        nullptr, nullptr, t2, nullptr);
    dwgelu_kernel<<<3136, 256, 0, stream>>>(t2, dwt, dsc, dsh, t3);
    // conv2 1x1 + folded BN3 + residual -> d_out (swizzled 392)
    mfma_gemm<3, 1><<<392, 256, 0, stream>>>(
        t3, wbf + 524288, MQ, 256, 1024, nullptr, dsc3, dsh3,
        x2c, nullptr, nullptr, outp);
}